// Round 4
// baseline (1100.560 us; speedup 1.0000x reference)
//
#include <hip/hip_runtime.h>
#include <hip/hip_bf16.h>
#include <math.h>

// Problem constants
#define BATCH 4
#define SEQ   2048
#define HID   768
#define INTER 1536
#define DK    128
#define NTOT  3200      // 2*INTER + DK
#define MROWS 8192      // BATCH*SEQ
#define LN512 6.2383246250395075f

typedef _Float16 half8  __attribute__((ext_vector_type(8)));
typedef float    floatx4 __attribute__((ext_vector_type(4)));

// ---------------------------------------------------------------- prep kernels
__global__ void cast_h_kernel(const float* __restrict__ in, _Float16* __restrict__ out, int n) {
    int i = blockIdx.x * blockDim.x + threadIdx.x;
    if (i < n) out[i] = (_Float16)in[i];
}

__global__ void trans_wi_kernel(const float* __restrict__ Wi, _Float16* __restrict__ WiT) {
    int i = blockIdx.x * blockDim.x + threadIdx.x;  // over HID*NTOT, coalesced read
    if (i < HID * NTOT) {
        int r = i / NTOT, c = i - r * NTOT;
        WiT[c * HID + r] = (_Float16)Wi[i];
    }
}

__global__ void trans_wo_kernel(const float* __restrict__ Wo, _Float16* __restrict__ WoT) {
    int i = blockIdx.x * blockDim.x + threadIdx.x;  // over INTER*HID
    if (i < INTER * HID) {
        int r = i / HID, c = i - r * HID;
        WoT[c * INTER + r] = (_Float16)Wo[i];
    }
}

__global__ void mask_scales_kernel(const int* __restrict__ mask, float* __restrict__ scales) {
    __shared__ int sh[256];
    int b = blockIdx.x;
    int s = 0;
    for (int i = threadIdx.x; i < SEQ; i += 256) s += mask[b * SEQ + i];
    sh[threadIdx.x] = s;
    __syncthreads();
    for (int off = 128; off > 0; off >>= 1) {
        if (threadIdx.x < off) sh[threadIdx.x] += sh[threadIdx.x + off];
        __syncthreads();
    }
    if (threadIdx.x == 0) scales[b] = logf((float)sh[0]) / LN512;
}

// ---------------------------------------------------------------- GEMM1: silu(H@Wi) -> u, vT, q, k
// A = Hb (MROWS x HID, row-major f16). B = WiT (NTOT x HID, row-major f16: BT[n][k]).
// Block: 256 thr = 4 waves; block tile 64(M) x 64(N); wave = 16(M) x 64(N).
__global__ __launch_bounds__(256) void gemm1_kernel(
    const _Float16* __restrict__ Hb, const _Float16* __restrict__ WiT,
    const float* __restrict__ qg, const float* __restrict__ kg,
    _Float16* __restrict__ u, _Float16* __restrict__ vT,
    _Float16* __restrict__ q, _Float16* __restrict__ k)
{
    const int tid = threadIdx.x;
    const int wave = tid >> 6, lane = tid & 63, quad = lane >> 4, l16 = lane & 15;
    const int m0 = blockIdx.y * 64 + wave * 16;
    const int n0 = blockIdx.x * 64;

    const _Float16* arow = Hb + (m0 + l16) * HID + quad * 8;
    floatx4 acc[4] = {};
    for (int k0 = 0; k0 < HID; k0 += 32) {
        half8 a = *reinterpret_cast<const half8*>(arow + k0);
#pragma unroll
        for (int nt = 0; nt < 4; ++nt) {
            half8 bb = *reinterpret_cast<const half8*>(WiT + (n0 + nt * 16 + l16) * HID + k0 + quad * 8);
            acc[nt] = __builtin_amdgcn_mfma_f32_16x16x32_f16(a, bb, acc[nt], 0, 0, 0);
        }
    }
#pragma unroll
    for (int nt = 0; nt < 4; ++nt) {
        int col = n0 + nt * 16 + l16;
#pragma unroll
        for (int i = 0; i < 4; ++i) {
            int row = m0 + quad * 4 + i;
            float x = acc[nt][i];
            float y = x / (1.0f + __expf(-x));   // silu
            if (col < INTER) {
                u[row * INTER + col] = (_Float16)y;
            } else if (col < 2 * INTER) {
                int bb = row >> 11, s = row & (SEQ - 1), c = col - INTER;
                vT[((size_t)bb * INTER + c) * SEQ + s] = (_Float16)y;   // v transposed per batch
            } else {
                int c = col - 2 * INTER;
                q[row * DK + c] = (_Float16)(y * qg[c]);
                k[row * DK + c] = (_Float16)(y * kg[c]);
            }
        }
    }
}

// ---------------------------------------------------------------- scores + softmax -> P (f16)
// One block per (batch, 16-row m-tile). 4 waves split the 128 n-tiles (each wave 32 tiles).
__global__ __launch_bounds__(256) void scores_kernel(
    const _Float16* __restrict__ q, const _Float16* __restrict__ k,
    const int* __restrict__ mask, const float* __restrict__ scales,
    _Float16* __restrict__ P)
{
    const int b = blockIdx.y;
    const int m0 = blockIdx.x * 16;
    const int tid = threadIdx.x;
    const int wave = tid >> 6, lane = tid & 63, quad = lane >> 4, l16 = lane & 15;
    const float scale = scales[b];

    half8 aq[4];
    const _Float16* qrow = q + (b * SEQ + m0 + l16) * DK + quad * 8;
#pragma unroll
    for (int kk = 0; kk < 4; ++kk) aq[kk] = *reinterpret_cast<const half8*>(qrow + kk * 32);

    floatx4 sc[32];
#pragma unroll
    for (int nt = 0; nt < 32; ++nt) {
        int n0 = nt * 64 + wave * 16;
        const _Float16* krow = k + (b * SEQ + n0 + l16) * DK + quad * 8;
        floatx4 acc = {};
#pragma unroll
        for (int kk = 0; kk < 4; ++kk) {
            half8 bq = *reinterpret_cast<const half8*>(krow + kk * 32);
            acc = __builtin_amdgcn_mfma_f32_16x16x32_f16(aq[kk], bq, acc, 0, 0, 0);
        }
        sc[nt] = acc;
    }

    // scale + mask + row max.  C/D: col=lane&15, row=quad*4+i
    const float rs = 0.08838834764831845f * scale;  // 1/sqrt(128) * log(l)/log(512)
    const float mval = -1e12f * scale;
    float rmax[4] = {-3.4e38f, -3.4e38f, -3.4e38f, -3.4e38f};
#pragma unroll
    for (int nt = 0; nt < 32; ++nt) {
        int ncol = nt * 64 + wave * 16 + l16;
        bool mok = mask[b * SEQ + ncol] != 0;
#pragma unroll
        for (int i = 0; i < 4; ++i) {
            float s = mok ? sc[nt][i] * rs : mval;
            sc[nt][i] = s;
            rmax[i] = fmaxf(rmax[i], s);
        }
    }
#pragma unroll
    for (int i = 0; i < 4; ++i) {
#pragma unroll
        for (int off = 1; off < 16; off <<= 1)
            rmax[i] = fmaxf(rmax[i], __shfl_xor(rmax[i], off, 64));
    }
    __shared__ float redmax[4][16];
    __shared__ float redsum[4][16];
    if (l16 == 0) {
#pragma unroll
        for (int i = 0; i < 4; ++i) redmax[wave][quad * 4 + i] = rmax[i];
    }
    __syncthreads();
#pragma unroll
    for (int i = 0; i < 4; ++i) {
        int r = quad * 4 + i;
        rmax[i] = fmaxf(fmaxf(redmax[0][r], redmax[1][r]), fmaxf(redmax[2][r], redmax[3][r]));
    }
    float rsum[4] = {0.f, 0.f, 0.f, 0.f};
#pragma unroll
    for (int nt = 0; nt < 32; ++nt) {
#pragma unroll
        for (int i = 0; i < 4; ++i) {
            float e = __expf(sc[nt][i] - rmax[i]);
            sc[nt][i] = e;
            rsum[i] += e;
        }
    }
#pragma unroll
    for (int i = 0; i < 4; ++i) {
#pragma unroll
        for (int off = 1; off < 16; off <<= 1) rsum[i] += __shfl_xor(rsum[i], off, 64);
    }
    if (l16 == 0) {
#pragma unroll
        for (int i = 0; i < 4; ++i) redsum[wave][quad * 4 + i] = rsum[i];
    }
    __syncthreads();
#pragma unroll
    for (int i = 0; i < 4; ++i) {
        int r = quad * 4 + i;
        float tot = redsum[0][r] + redsum[1][r] + redsum[2][r] + redsum[3][r];
        float inv = 1.0f / tot;
        int row = m0 + r;
        _Float16* Prow = P + ((size_t)b * SEQ + row) * SEQ;
#pragma unroll
        for (int nt = 0; nt < 32; ++nt) {
            int ncol = nt * 64 + wave * 16 + l16;
            Prow[ncol] = (_Float16)(sc[nt][i] * inv);
        }
    }
}

// ---------------------------------------------------------------- PV: u <- u .* (P @ v)   (in place)
__global__ __launch_bounds__(256) void pv_kernel(
    const _Float16* __restrict__ P, const _Float16* __restrict__ vT,
    _Float16* __restrict__ u)
{
    const int b = blockIdx.z;
    const int tid = threadIdx.x;
    const int wave = tid >> 6, lane = tid & 63, quad = lane >> 4, l16 = lane & 15;
    const int m0 = blockIdx.y * 64 + wave * 16;
    const int n0 = blockIdx.x * 64;
    const _Float16* Pb  = P  + (size_t)b * SEQ * SEQ;
    const _Float16* vTb = vT + (size_t)b * INTER * SEQ;

    const _Float16* arow = Pb + (m0 + l16) * SEQ + quad * 8;
    floatx4 acc[4] = {};
    for (int k0 = 0; k0 < SEQ; k0 += 32) {
        half8 a = *reinterpret_cast<const half8*>(arow + k0);
#pragma unroll
        for (int nt = 0; nt < 4; ++nt) {
            half8 bb = *reinterpret_cast<const half8*>(vTb + (n0 + nt * 16 + l16) * SEQ + k0 + quad * 8);
            acc[nt] = __builtin_amdgcn_mfma_f32_16x16x32_f16(a, bb, acc[nt], 0, 0, 0);
        }
    }
#pragma unroll
    for (int nt = 0; nt < 4; ++nt) {
        int col = n0 + nt * 16 + l16;
#pragma unroll
        for (int i = 0; i < 4; ++i) {
            int row = m0 + quad * 4 + i;
            size_t gidx = ((size_t)(b * SEQ + row)) * INTER + col;
            float uv = (float)u[gidx];                      // read-once
            u[gidx] = (_Float16)(acc[nt][i] * uv);          // write-once, same thread
        }
    }
}

// ---------------------------------------------------------------- GEMM2: out = t @ Wo (fp32 out)
__global__ __launch_bounds__(256) void gemm2_kernel(
    const _Float16* __restrict__ t, const _Float16* __restrict__ WoT,
    float* __restrict__ out)
{
    const int tid = threadIdx.x;
    const int wave = tid >> 6, lane = tid & 63, quad = lane >> 4, l16 = lane & 15;
    const int m0 = blockIdx.y * 64 + wave * 16;
    const int n0 = blockIdx.x * 64;

    const _Float16* arow = t + (size_t)(m0 + l16) * INTER + quad * 8;
    floatx4 acc[4] = {};
    for (int k0 = 0; k0 < INTER; k0 += 32) {
        half8 a = *reinterpret_cast<const half8*>(arow + k0);
#pragma unroll
        for (int nt = 0; nt < 4; ++nt) {
            half8 bb = *reinterpret_cast<const half8*>(WoT + (n0 + nt * 16 + l16) * INTER + k0 + quad * 8);
            acc[nt] = __builtin_amdgcn_mfma_f32_16x16x32_f16(a, bb, acc[nt], 0, 0, 0);
        }
    }
#pragma unroll
    for (int nt = 0; nt < 4; ++nt) {
        int col = n0 + nt * 16 + l16;
#pragma unroll
        for (int i = 0; i < 4; ++i) {
            int row = m0 + quad * 4 + i;
            out[(size_t)row * HID + col] = acc[nt][i];   // fp32 output (reference dtype)
        }
    }
}

// ---------------------------------------------------------------- launch
extern "C" void kernel_launch(void* const* d_in, const int* in_sizes, int n_in,
                              void* d_out, int out_size, void* d_ws, size_t ws_size,
                              hipStream_t stream) {
    const float* H    = (const float*)d_in[0];   // fp32 (reference dtypes)
    const float* Wi   = (const float*)d_in[1];
    const float* Wo   = (const float*)d_in[2];
    const float* qg   = (const float*)d_in[3];
    const float* kg   = (const float*)d_in[4];
    const int*   mask = (const int*)d_in[5];
    float* out = (float*)d_out;                  // fp32 output (reference dtype)

    // workspace layout (256B aligned), total ~108 MB
    char* base = (char*)d_ws;
    size_t off = 0;
    auto alloc = [&](size_t bytes) { void* p = base + off; off = (off + bytes + 255) & ~(size_t)255; return p; };
    _Float16* Hb   = (_Float16*)alloc((size_t)MROWS * HID * 2);
    _Float16* WiT  = (_Float16*)alloc((size_t)NTOT * HID * 2);
    _Float16* WoT  = (_Float16*)alloc((size_t)HID * INTER * 2);
    _Float16* u    = (_Float16*)alloc((size_t)MROWS * INTER * 2);   // becomes t in-place after pv
    _Float16* vT   = (_Float16*)alloc((size_t)BATCH * INTER * SEQ * 2);
    _Float16* q    = (_Float16*)alloc((size_t)MROWS * DK * 2);
    _Float16* k    = (_Float16*)alloc((size_t)MROWS * DK * 2);
    _Float16* P    = (_Float16*)alloc((size_t)BATCH * SEQ * SEQ * 2);
    float*    scales = (float*)alloc(4 * sizeof(float));

    // prep
    {
        int n = MROWS * HID;
        cast_h_kernel<<<(n + 255) / 256, 256, 0, stream>>>(H, Hb, n);
        trans_wi_kernel<<<(HID * NTOT + 255) / 256, 256, 0, stream>>>(Wi, WiT);
        trans_wo_kernel<<<(INTER * HID + 255) / 256, 256, 0, stream>>>(Wo, WoT);
        mask_scales_kernel<<<BATCH, 256, 0, stream>>>(mask, scales);
    }
    // GEMM1: silu(H@Wi) -> u, vT, q, k
    {
        dim3 grid(NTOT / 64, MROWS / 64);
        gemm1_kernel<<<grid, 256, 0, stream>>>(Hb, WiT, qg, kg, u, vT, q, k);
    }
    // scores + softmax -> P
    {
        dim3 grid(SEQ / 16, BATCH);
        scores_kernel<<<grid, 256, 0, stream>>>(q, k, mask, scales, P);
    }
    // PV: u <- u .* (P@v)  (in place)
    {
        dim3 grid(INTER / 64, SEQ / 64, BATCH);
        pv_kernel<<<grid, 256, 0, stream>>>(P, vT, u);
    }
    // GEMM2: out = u @ Wo
    {
        dim3 grid(HID / 64, MROWS / 64);
        gemm2_kernel<<<grid, 256, 0, stream>>>(u, WoT, out);
    }
}

// Round 5
// 394.507 us; speedup vs baseline: 2.7897x; 2.7897x over previous
//
#include <hip/hip_runtime.h>
#include <hip/hip_bf16.h>
#include <math.h>

// Problem constants
#define BATCH 4
#define SEQ   2048
#define HID   768
#define INTER 1536
#define DK    128
#define NTOT  3200      // 2*INTER + DK
#define MROWS 8192      // BATCH*SEQ
#define LN512 6.2383246250395075f

typedef _Float16 half8  __attribute__((ext_vector_type(8)));
typedef float    floatx4 __attribute__((ext_vector_type(4)));

typedef const __attribute__((address_space(1))) unsigned int* gas1_t;
typedef __attribute__((address_space(3))) unsigned int* las3_t;

static __device__ __forceinline__ void load16(const _Float16* g, _Float16* l) {
    __builtin_amdgcn_global_load_lds((gas1_t)g, (las3_t)l, 16, 0, 0);
}

// ---------------------------------------------------------------- prep kernels
__global__ void cast_h_kernel(const float* __restrict__ in, _Float16* __restrict__ out, int n) {
    int i = blockIdx.x * blockDim.x + threadIdx.x;
    if (i < n) out[i] = (_Float16)in[i];
}

__global__ void trans_wi_kernel(const float* __restrict__ Wi, _Float16* __restrict__ WiT) {
    int i = blockIdx.x * blockDim.x + threadIdx.x;  // over HID*NTOT, coalesced read
    if (i < HID * NTOT) {
        int r = i / NTOT, c = i - r * NTOT;
        WiT[c * HID + r] = (_Float16)Wi[i];
    }
}

__global__ void trans_wo_kernel(const float* __restrict__ Wo, _Float16* __restrict__ WoT) {
    int i = blockIdx.x * blockDim.x + threadIdx.x;  // over INTER*HID
    if (i < INTER * HID) {
        int r = i / HID, c = i - r * HID;
        WoT[c * INTER + r] = (_Float16)Wo[i];
    }
}

__global__ void mask_scales_kernel(const int* __restrict__ mask, float* __restrict__ scales) {
    __shared__ int sh[256];
    int b = blockIdx.x;
    int s = 0;
    for (int i = threadIdx.x; i < SEQ; i += 256) s += mask[b * SEQ + i];
    sh[threadIdx.x] = s;
    __syncthreads();
    for (int off = 128; off > 0; off >>= 1) {
        if (threadIdx.x < off) sh[threadIdx.x] += sh[threadIdx.x + off];
        __syncthreads();
    }
    if (threadIdx.x == 0) scales[b] = logf((float)sh[0]) / LN512;
}

// ---------------------------------------------------------------- tiled GEMM mainloop (m97 structure)
// C(128x128) += A(128xK) * BT(128xK)^T at block (m0 rows of A, n0 rows of BT).
// 256 threads = 4 waves in 2x2; wave computes 64x64 = 4x4 MFMA 16x16x32 tiles.
// As/Bs: 128 rows x 32 k f16, row-major (row stride 64B). Staged via global_load_lds w=16.
struct TileCtx {
    int tid, wave, lane, quad, l16, wm, wn, c0, c1;
};
static __device__ __forceinline__ TileCtx make_ctx() {
    TileCtx t;
    t.tid = threadIdx.x;
    t.wave = t.tid >> 6; t.lane = t.tid & 63;
    t.quad = t.lane >> 4; t.l16 = t.lane & 15;
    t.wm = (t.wave & 1) * 64;    // wave m-offset in tile
    t.wn = (t.wave >> 1) * 64;   // wave n-offset in tile
    t.c0 = t.tid;                // staging chunk ids (16B each), 512 chunks per 8KB tile
    t.c1 = t.tid + 256;
    return t;
}

static __device__ __forceinline__ void gemm_mainloop(
    const TileCtx& t,
    const _Float16* __restrict__ Ag, int lda,   // &A[m0][0]
    const _Float16* __restrict__ Bg, int ldb,   // &BT[n0][0]
    int K, _Float16* As, _Float16* Bs,
    floatx4 acc[4][4])
{
    const int ar0 = t.c0 >> 2, ak0 = (t.c0 & 3) * 8;
    const int ar1 = t.c1 >> 2, ak1 = (t.c1 & 3) * 8;
    for (int k0 = 0; k0 < K; k0 += 32) {
        __syncthreads();   // previous tile fully consumed
        load16(Ag + (size_t)ar0 * lda + k0 + ak0, As + t.c0 * 8);
        load16(Ag + (size_t)ar1 * lda + k0 + ak1, As + t.c1 * 8);
        load16(Bg + (size_t)ar0 * ldb + k0 + ak0, Bs + t.c0 * 8);
        load16(Bg + (size_t)ar1 * ldb + k0 + ak1, Bs + t.c1 * 8);
        __syncthreads();   // staged (compiler inserts vmcnt(0) drain before barrier)
        half8 af[4], bf[4];
#pragma unroll
        for (int mt = 0; mt < 4; ++mt)
            af[mt] = *reinterpret_cast<const half8*>(As + (t.wm + mt * 16 + t.l16) * 32 + t.quad * 8);
#pragma unroll
        for (int nt = 0; nt < 4; ++nt)
            bf[nt] = *reinterpret_cast<const half8*>(Bs + (t.wn + nt * 16 + t.l16) * 32 + t.quad * 8);
#pragma unroll
        for (int mt = 0; mt < 4; ++mt)
#pragma unroll
            for (int nt = 0; nt < 4; ++nt)
                acc[mt][nt] = __builtin_amdgcn_mfma_f32_16x16x32_f16(af[mt], bf[nt], acc[mt][nt], 0, 0, 0);
    }
}

// ---------------------------------------------------------------- GEMM1: silu(H@Wi) -> u, vT, q, k
__global__ __launch_bounds__(256) void gemm1_kernel(
    const _Float16* __restrict__ Hb, const _Float16* __restrict__ WiT,
    const float* __restrict__ qg, const float* __restrict__ kg,
    _Float16* __restrict__ u, _Float16* __restrict__ vT,
    _Float16* __restrict__ q, _Float16* __restrict__ k)
{
    __shared__ _Float16 As[128 * 32];
    __shared__ _Float16 Bs[128 * 32];
    TileCtx t = make_ctx();
    const int m0 = blockIdx.y * 128;
    const int n0 = blockIdx.x * 128;

    floatx4 acc[4][4] = {};
    gemm_mainloop(t, Hb + (size_t)m0 * HID, HID, WiT + (size_t)n0 * HID, HID, HID, As, Bs, acc);

    // whole block's 128-col range sits in exactly one region (boundaries are multiples of 128)
#pragma unroll
    for (int mt = 0; mt < 4; ++mt) {
#pragma unroll
        for (int nt = 0; nt < 4; ++nt) {
            int col = n0 + t.wn + nt * 16 + t.l16;
#pragma unroll
            for (int i = 0; i < 4; ++i) {
                int row = m0 + t.wm + mt * 16 + t.quad * 4 + i;
                float x = acc[mt][nt][i];
                float y = x / (1.0f + __expf(-x));   // silu
                if (n0 < INTER) {
                    u[(size_t)row * INTER + col] = (_Float16)y;
                } else if (n0 < 2 * INTER) {
                    int bb = row >> 11, s = row & (SEQ - 1), c = col - INTER;
                    vT[((size_t)bb * INTER + c) * SEQ + s] = (_Float16)y;
                } else {
                    int c = col - 2 * INTER;
                    q[(size_t)row * DK + c] = (_Float16)(y * qg[c]);
                    k[(size_t)row * DK + c] = (_Float16)(y * kg[c]);
                }
            }
        }
    }
}

// ---------------------------------------------------------------- scores + softmax -> P (f16)
__global__ __launch_bounds__(256) void scores_kernel(
    const _Float16* __restrict__ q, const _Float16* __restrict__ k,
    const int* __restrict__ mask, const float* __restrict__ scales,
    _Float16* __restrict__ P)
{
    const int b = blockIdx.y;
    const int m0 = blockIdx.x * 16;
    const int tid = threadIdx.x;
    const int wave = tid >> 6, lane = tid & 63, quad = lane >> 4, l16 = lane & 15;
    const float scale = scales[b];

    half8 aq[4];
    const _Float16* qrow = q + (b * SEQ + m0 + l16) * DK + quad * 8;
#pragma unroll
    for (int kk = 0; kk < 4; ++kk) aq[kk] = *reinterpret_cast<const half8*>(qrow + kk * 32);

    floatx4 sc[32];
#pragma unroll
    for (int nt = 0; nt < 32; ++nt) {
        int n0 = nt * 64 + wave * 16;
        const _Float16* krow = k + (b * SEQ + n0 + l16) * DK + quad * 8;
        floatx4 acc = {};
#pragma unroll
        for (int kk = 0; kk < 4; ++kk) {
            half8 bq = *reinterpret_cast<const half8*>(krow + kk * 32);
            acc = __builtin_amdgcn_mfma_f32_16x16x32_f16(aq[kk], bq, acc, 0, 0, 0);
        }
        sc[nt] = acc;
    }

    const float rs = 0.08838834764831845f * scale;  // 1/sqrt(128) * log(l)/log(512)
    const float mval = -1e12f * scale;
    float rmax[4] = {-3.4e38f, -3.4e38f, -3.4e38f, -3.4e38f};
#pragma unroll
    for (int nt = 0; nt < 32; ++nt) {
        int ncol = nt * 64 + wave * 16 + l16;
        bool mok = mask[b * SEQ + ncol] != 0;
#pragma unroll
        for (int i = 0; i < 4; ++i) {
            float s = mok ? sc[nt][i] * rs : mval;
            sc[nt][i] = s;
            rmax[i] = fmaxf(rmax[i], s);
        }
    }
#pragma unroll
    for (int i = 0; i < 4; ++i) {
#pragma unroll
        for (int off = 1; off < 16; off <<= 1)
            rmax[i] = fmaxf(rmax[i], __shfl_xor(rmax[i], off, 64));
    }
    __shared__ float redmax[4][16];
    __shared__ float redsum[4][16];
    if (l16 == 0) {
#pragma unroll
        for (int i = 0; i < 4; ++i) redmax[wave][quad * 4 + i] = rmax[i];
    }
    __syncthreads();
#pragma unroll
    for (int i = 0; i < 4; ++i) {
        int r = quad * 4 + i;
        rmax[i] = fmaxf(fmaxf(redmax[0][r], redmax[1][r]), fmaxf(redmax[2][r], redmax[3][r]));
    }
    float rsum[4] = {0.f, 0.f, 0.f, 0.f};
#pragma unroll
    for (int nt = 0; nt < 32; ++nt) {
#pragma unroll
        for (int i = 0; i < 4; ++i) {
            float e = __expf(sc[nt][i] - rmax[i]);
            sc[nt][i] = e;
            rsum[i] += e;
        }
    }
#pragma unroll
    for (int i = 0; i < 4; ++i) {
#pragma unroll
        for (int off = 1; off < 16; off <<= 1) rsum[i] += __shfl_xor(rsum[i], off, 64);
    }
    if (l16 == 0) {
#pragma unroll
        for (int i = 0; i < 4; ++i) redsum[wave][quad * 4 + i] = rsum[i];
    }
    __syncthreads();
#pragma unroll
    for (int i = 0; i < 4; ++i) {
        int r = quad * 4 + i;
        float tot = redsum[0][r] + redsum[1][r] + redsum[2][r] + redsum[3][r];
        float inv = 1.0f / tot;
        int row = m0 + r;
        _Float16* Prow = P + ((size_t)b * SEQ + row) * SEQ;
#pragma unroll
        for (int nt = 0; nt < 32; ++nt) {
            int ncol = nt * 64 + wave * 16 + l16;
            Prow[ncol] = (_Float16)(sc[nt][i] * inv);
        }
    }
}

// ---------------------------------------------------------------- PV: u <- u .* (P @ v)   (in place)
__global__ __launch_bounds__(256) void pv_kernel(
    const _Float16* __restrict__ P, const _Float16* __restrict__ vT,
    _Float16* __restrict__ u)
{
    __shared__ _Float16 As[128 * 32];
    __shared__ _Float16 Bs[128 * 32];
    TileCtx t = make_ctx();
    const int b = blockIdx.z;
    const int m0 = blockIdx.y * 128;
    const int n0 = blockIdx.x * 128;
    const _Float16* Pb  = P  + (size_t)b * SEQ * SEQ;
    const _Float16* vTb = vT + (size_t)b * INTER * SEQ;

    floatx4 acc[4][4] = {};
    gemm_mainloop(t, Pb + (size_t)m0 * SEQ, SEQ, vTb + (size_t)n0 * SEQ, SEQ, SEQ, As, Bs, acc);

#pragma unroll
    for (int mt = 0; mt < 4; ++mt) {
#pragma unroll
        for (int nt = 0; nt < 4; ++nt) {
            int col = n0 + t.wn + nt * 16 + t.l16;
#pragma unroll
            for (int i = 0; i < 4; ++i) {
                int row = m0 + t.wm + mt * 16 + t.quad * 4 + i;
                size_t gidx = ((size_t)(b * SEQ + row)) * INTER + col;
                float uv = (float)u[gidx];
                u[gidx] = (_Float16)(acc[mt][nt][i] * uv);
            }
        }
    }
}

// ---------------------------------------------------------------- GEMM2: out = t @ Wo (fp32 out)
__global__ __launch_bounds__(256) void gemm2_kernel(
    const _Float16* __restrict__ tin, const _Float16* __restrict__ WoT,
    float* __restrict__ out)
{
    __shared__ _Float16 As[128 * 32];
    __shared__ _Float16 Bs[128 * 32];
    TileCtx t = make_ctx();
    const int m0 = blockIdx.y * 128;
    const int n0 = blockIdx.x * 128;

    floatx4 acc[4][4] = {};
    gemm_mainloop(t, tin + (size_t)m0 * INTER, INTER, WoT + (size_t)n0 * INTER, INTER, INTER, As, Bs, acc);

#pragma unroll
    for (int mt = 0; mt < 4; ++mt) {
#pragma unroll
        for (int nt = 0; nt < 4; ++nt) {
            int col = n0 + t.wn + nt * 16 + t.l16;
#pragma unroll
            for (int i = 0; i < 4; ++i) {
                int row = m0 + t.wm + mt * 16 + t.quad * 4 + i;
                out[(size_t)row * HID + col] = acc[mt][nt][i];
            }
        }
    }
}

// ---------------------------------------------------------------- launch
extern "C" void kernel_launch(void* const* d_in, const int* in_sizes, int n_in,
                              void* d_out, int out_size, void* d_ws, size_t ws_size,
                              hipStream_t stream) {
    const float* H    = (const float*)d_in[0];
    const float* Wi   = (const float*)d_in[1];
    const float* Wo   = (const float*)d_in[2];
    const float* qg   = (const float*)d_in[3];
    const float* kg   = (const float*)d_in[4];
    const int*   mask = (const int*)d_in[5];
    float* out = (float*)d_out;

    // workspace layout (256B aligned), total ~108 MB
    char* base = (char*)d_ws;
    size_t off = 0;
    auto alloc = [&](size_t bytes) { void* p = base + off; off = (off + bytes + 255) & ~(size_t)255; return p; };
    _Float16* Hb   = (_Float16*)alloc((size_t)MROWS * HID * 2);
    _Float16* WiT  = (_Float16*)alloc((size_t)NTOT * HID * 2);
    _Float16* WoT  = (_Float16*)alloc((size_t)HID * INTER * 2);
    _Float16* u    = (_Float16*)alloc((size_t)MROWS * INTER * 2);   // becomes t in-place after pv
    _Float16* vT   = (_Float16*)alloc((size_t)BATCH * INTER * SEQ * 2);
    _Float16* q    = (_Float16*)alloc((size_t)MROWS * DK * 2);
    _Float16* k    = (_Float16*)alloc((size_t)MROWS * DK * 2);
    _Float16* P    = (_Float16*)alloc((size_t)BATCH * SEQ * SEQ * 2);
    float*    scales = (float*)alloc(4 * sizeof(float));

    // prep
    {
        int n = MROWS * HID;
        cast_h_kernel<<<(n + 255) / 256, 256, 0, stream>>>(H, Hb, n);
        trans_wi_kernel<<<(HID * NTOT + 255) / 256, 256, 0, stream>>>(Wi, WiT);
        trans_wo_kernel<<<(INTER * HID + 255) / 256, 256, 0, stream>>>(Wo, WoT);
        mask_scales_kernel<<<BATCH, 256, 0, stream>>>(mask, scales);
    }
    // GEMM1: silu(H@Wi) -> u, vT, q, k      M=8192 N=3200 K=768
    {
        dim3 grid(NTOT / 128, MROWS / 128);
        gemm1_kernel<<<grid, 256, 0, stream>>>(Hb, WiT, qg, kg, u, vT, q, k);
    }
    // scores + softmax -> P
    {
        dim3 grid(SEQ / 16, BATCH);
        scores_kernel<<<grid, 256, 0, stream>>>(q, k, mask, scales, P);
    }
    // PV: u <- u .* (P@v)   per batch M=2048 N=1536 K=2048
    {
        dim3 grid(INTER / 128, SEQ / 128, BATCH);
        pv_kernel<<<grid, 256, 0, stream>>>(P, vT, u);
    }
    // GEMM2: out = u @ Wo   M=8192 N=768 K=1536
    {
        dim3 grid(HID / 128, MROWS / 128);
        gemm2_kernel<<<grid, 256, 0, stream>>>(u, WoT, out);
    }
}

// Round 7
// 359.457 us; speedup vs baseline: 3.0617x; 1.0975x over previous
//
#include <hip/hip_runtime.h>
#include <hip/hip_bf16.h>
#include <math.h>

// Problem constants
#define BATCH 4
#define SEQ   2048
#define HID   768
#define INTER 1536
#define DK    128
#define NTOT  3200      // 2*INTER + DK
#define MROWS 8192      // BATCH*SEQ
#define LN512 6.2383246250395075f

typedef _Float16 half8  __attribute__((ext_vector_type(8)));
typedef float    floatx4 __attribute__((ext_vector_type(4)));

typedef const __attribute__((address_space(1))) unsigned int* gas1_t;
typedef __attribute__((address_space(3))) unsigned int* las3_t;

static __device__ __forceinline__ void load16(const _Float16* g, _Float16* l) {
    __builtin_amdgcn_global_load_lds((gas1_t)g, (las3_t)l, 16, 0, 0);
}
// Compiler-opaque barriers/waits: memory clobber pins ordering at IR level;
// hardware waits only the stated vmcnt (never a full drain mid-loop).
#define WAIT_VM(N)  asm volatile("s_waitcnt vmcnt(" #N ")" ::: "memory")
#define BARRIER_RAW() asm volatile("s_barrier" ::: "memory")

// ---------------------------------------------------------------- prep kernels
__global__ void cast_h_kernel(const float* __restrict__ in, _Float16* __restrict__ out, int n) {
    int i = blockIdx.x * blockDim.x + threadIdx.x;
    if (i < n) out[i] = (_Float16)in[i];
}

__global__ void trans_wi_kernel(const float* __restrict__ Wi, _Float16* __restrict__ WiT) {
    int i = blockIdx.x * blockDim.x + threadIdx.x;
    if (i < HID * NTOT) {
        int r = i / NTOT, c = i - r * NTOT;
        WiT[c * HID + r] = (_Float16)Wi[i];
    }
}

__global__ void trans_wo_kernel(const float* __restrict__ Wo, _Float16* __restrict__ WoT) {
    int i = blockIdx.x * blockDim.x + threadIdx.x;
    if (i < INTER * HID) {
        int r = i / HID, c = i - r * HID;
        WoT[c * INTER + r] = (_Float16)Wo[i];
    }
}

__global__ void mask_scales_kernel(const int* __restrict__ mask, float* __restrict__ scales) {
    __shared__ int sh[256];
    int b = blockIdx.x;
    int s = 0;
    for (int i = threadIdx.x; i < SEQ; i += 256) s += mask[b * SEQ + i];
    sh[threadIdx.x] = s;
    __syncthreads();
    for (int off = 128; off > 0; off >>= 1) {
        if (threadIdx.x < off) sh[threadIdx.x] += sh[threadIdx.x + off];
        __syncthreads();
    }
    if (threadIdx.x == 0) scales[b] = logf((float)sh[0]) / LN512;
}

// ---------------------------------------------------------------- tiled GEMM mainloop, double-buffered
// C(128x128) += A(128xK) * BT(128xK)^T. 256 thr = 4 waves 2x2; wave does 64x64.
// smem halves: A bufs [0,4096),[4096,8192); B bufs [8192,12288),[12288,16384).
// Pipeline: issue tile k+1 DMA into other buffer, wait vmcnt(4) (own tile-k loads
// landed; 4 prefetches stay in flight), raw barrier, ds_read+MFMA, raw barrier.
struct TileCtx {
    int tid, wave, lane, quad, l16, wm, wn, c0, c1;
};
static __device__ __forceinline__ TileCtx make_ctx() {
    TileCtx t;
    t.tid = threadIdx.x;
    t.wave = t.tid >> 6; t.lane = t.tid & 63;
    t.quad = t.lane >> 4; t.l16 = t.lane & 15;
    t.wm = (t.wave & 1) * 64;
    t.wn = (t.wave >> 1) * 64;
    t.c0 = t.tid;
    t.c1 = t.tid + 256;
    return t;
}

static __device__ __forceinline__ void gemm_mainloop_db(
    const TileCtx& t,
    const _Float16* __restrict__ Ag, int lda,   // &A[m0][0]
    const _Float16* __restrict__ Bg, int ldb,   // &BT[n0][0]
    int K, _Float16* smem, floatx4 acc[4][4])
{
    const int ar0 = t.c0 >> 2, ak0 = (t.c0 & 3) * 8;
    const int ar1 = t.c1 >> 2, ak1 = (t.c1 & 3) * 8;
    const _Float16* a0 = Ag + (size_t)ar0 * lda + ak0;
    const _Float16* a1 = Ag + (size_t)ar1 * lda + ak1;
    const _Float16* b0 = Bg + (size_t)ar0 * ldb + ak0;
    const _Float16* b1 = Bg + (size_t)ar1 * ldb + ak1;
    _Float16* Asl = smem + t.c0 * 8;           // my A staging slot (buffer 0)
    _Float16* Bsl = smem + 8192 + t.c0 * 8;    // my B staging slot (buffer 0)

    // prologue: tile 0 -> buffer 0
    load16(a0, Asl);
    load16(a1, Asl + 2048);
    load16(b0, Bsl);
    load16(b1, Bsl + 2048);

    int buf = 0;
    for (int k0 = 0; k0 < K; k0 += 32) {
        if (k0 + 32 < K) {
            const int nb = (buf ^ 1) * 4096;
            load16(a0 + k0 + 32, Asl + nb);
            load16(a1 + k0 + 32, Asl + nb + 2048);
            load16(b0 + k0 + 32, Bsl + nb);
            load16(b1 + k0 + 32, Bsl + nb + 2048);
            WAIT_VM(4);    // my tile-k loads landed; 4 prefetches remain in flight
        } else {
            WAIT_VM(0);    // tail: drain
        }
        BARRIER_RAW();     // all waves' tile-k loads landed
        const _Float16* Ab = smem + buf * 4096;
        const _Float16* Bb = smem + 8192 + buf * 4096;
        half8 af[4], bf[4];
#pragma unroll
        for (int mt = 0; mt < 4; ++mt)
            af[mt] = *reinterpret_cast<const half8*>(Ab + (t.wm + mt * 16 + t.l16) * 32 + t.quad * 8);
#pragma unroll
        for (int nt = 0; nt < 4; ++nt)
            bf[nt] = *reinterpret_cast<const half8*>(Bb + (t.wn + nt * 16 + t.l16) * 32 + t.quad * 8);
#pragma unroll
        for (int mt = 0; mt < 4; ++mt)
#pragma unroll
            for (int nt = 0; nt < 4; ++nt)
                acc[mt][nt] = __builtin_amdgcn_mfma_f32_16x16x32_f16(af[mt], bf[nt], acc[mt][nt], 0, 0, 0);
        BARRIER_RAW();     // all waves done reading buf (ds_reads consumed by MFMA)
        buf ^= 1;
    }
}

// ---------------------------------------------------------------- GEMM1: silu(H@Wi) -> u, vT, q, k
__global__ __launch_bounds__(256) void gemm1_kernel(
    const _Float16* __restrict__ Hb, const _Float16* __restrict__ WiT,
    const float* __restrict__ qg, const float* __restrict__ kg,
    _Float16* __restrict__ u, _Float16* __restrict__ vT,
    _Float16* __restrict__ q, _Float16* __restrict__ k)
{
    __shared__ _Float16 smem[16384];
    TileCtx t = make_ctx();
    const int m0 = blockIdx.y * 128;
    const int n0 = blockIdx.x * 128;

    floatx4 acc[4][4] = {};
    gemm_mainloop_db(t, Hb + (size_t)m0 * HID, HID, WiT + (size_t)n0 * HID, HID, HID, smem, acc);

    if (n0 >= INTER && n0 < 2 * INTER) {
        // vT path: transpose via LDS (XOR swizzle on s-bits >=3), then coalesced 16B stores.
        const int bb = m0 >> 11, sloc = m0 & (SEQ - 1), cI = n0 - INTER;
#pragma unroll
        for (int mt = 0; mt < 4; ++mt) {
#pragma unroll
            for (int nt = 0; nt < 4; ++nt) {
                int c = t.wn + nt * 16 + t.l16;
#pragma unroll
                for (int i = 0; i < 4; ++i) {
                    int r = t.wm + mt * 16 + t.quad * 4 + i;
                    float x = acc[mt][nt][i];
                    float y = x / (1.0f + __expf(-x));   // silu
                    smem[c * 128 + (r ^ ((c & 15) << 3))] = (_Float16)y;
                }
            }
        }
        __syncthreads();
#pragma unroll
        for (int p = 0; p < 8; ++p) {
            int chunk = t.tid + p * 256;         // 2048 chunks of 8 halves (128x128 tile)
            int cl = chunk >> 4, sc = chunk & 15;
            int scs = sc ^ (cl & 15);
            half8 v = *reinterpret_cast<const half8*>(smem + cl * 128 + scs * 8);
            *reinterpret_cast<half8*>(vT + ((size_t)bb * INTER + cI + cl) * SEQ + sloc + sc * 8) = v;
        }
    } else {
#pragma unroll
        for (int mt = 0; mt < 4; ++mt) {
#pragma unroll
            for (int nt = 0; nt < 4; ++nt) {
                int col = n0 + t.wn + nt * 16 + t.l16;
#pragma unroll
                for (int i = 0; i < 4; ++i) {
                    int row = m0 + t.wm + mt * 16 + t.quad * 4 + i;
                    float x = acc[mt][nt][i];
                    float y = x / (1.0f + __expf(-x));   // silu
                    if (n0 < INTER) {
                        u[(size_t)row * INTER + col] = (_Float16)y;
                    } else {
                        int c = col - 2 * INTER;
                        q[(size_t)row * DK + c] = (_Float16)(y * qg[c]);
                        k[(size_t)row * DK + c] = (_Float16)(y * kg[c]);
                    }
                }
            }
        }
    }
}

// ---------------------------------------------------------------- scores + softmax -> P (f16)
__global__ __launch_bounds__(256) void scores_kernel(
    const _Float16* __restrict__ q, const _Float16* __restrict__ k,
    const int* __restrict__ mask, const float* __restrict__ scales,
    _Float16* __restrict__ P)
{
    const int b = blockIdx.y;
    const int m0 = blockIdx.x * 16;
    const int tid = threadIdx.x;
    const int wave = tid >> 6, lane = tid & 63, quad = lane >> 4, l16 = lane & 15;
    const float scale = scales[b];

    half8 aq[4];
    const _Float16* qrow = q + (b * SEQ + m0 + l16) * DK + quad * 8;
#pragma unroll
    for (int kk = 0; kk < 4; ++kk) aq[kk] = *reinterpret_cast<const half8*>(qrow + kk * 32);

    floatx4 sc[32];
#pragma unroll
    for (int nt = 0; nt < 32; ++nt) {
        int n0 = nt * 64 + wave * 16;
        const _Float16* krow = k + (b * SEQ + n0 + l16) * DK + quad * 8;
        floatx4 acc = {};
#pragma unroll
        for (int kk = 0; kk < 4; ++kk) {
            half8 bq = *reinterpret_cast<const half8*>(krow + kk * 32);
            acc = __builtin_amdgcn_mfma_f32_16x16x32_f16(aq[kk], bq, acc, 0, 0, 0);
        }
        sc[nt] = acc;
    }

    const float rs = 0.08838834764831845f * scale;
    const float mval = -1e12f * scale;
    float rmax[4] = {-3.4e38f, -3.4e38f, -3.4e38f, -3.4e38f};
#pragma unroll
    for (int nt = 0; nt < 32; ++nt) {
        int ncol = nt * 64 + wave * 16 + l16;
        bool mok = mask[b * SEQ + ncol] != 0;
#pragma unroll
        for (int i = 0; i < 4; ++i) {
            float s = mok ? sc[nt][i] * rs : mval;
            sc[nt][i] = s;
            rmax[i] = fmaxf(rmax[i], s);
        }
    }
#pragma unroll
    for (int i = 0; i < 4; ++i) {
#pragma unroll
        for (int off = 1; off < 16; off <<= 1)
            rmax[i] = fmaxf(rmax[i], __shfl_xor(rmax[i], off, 64));
    }
    __shared__ float redmax[4][16];
    __shared__ float redsum[4][16];
    if (l16 == 0) {
#pragma unroll
        for (int i = 0; i < 4; ++i) redmax[wave][quad * 4 + i] = rmax[i];
    }
    __syncthreads();
#pragma unroll
    for (int i = 0; i < 4; ++i) {
        int r = quad * 4 + i;
        rmax[i] = fmaxf(fmaxf(redmax[0][r], redmax[1][r]), fmaxf(redmax[2][r], redmax[3][r]));
    }
    float rsum[4] = {0.f, 0.f, 0.f, 0.f};
#pragma unroll
    for (int nt = 0; nt < 32; ++nt) {
#pragma unroll
        for (int i = 0; i < 4; ++i) {
            float e = __expf(sc[nt][i] - rmax[i]);
            sc[nt][i] = e;
            rsum[i] += e;
        }
    }
#pragma unroll
    for (int i = 0; i < 4; ++i) {
#pragma unroll
        for (int off = 1; off < 16; off <<= 1) rsum[i] += __shfl_xor(rsum[i], off, 64);
    }
    if (l16 == 0) {
#pragma unroll
        for (int i = 0; i < 4; ++i) redsum[wave][quad * 4 + i] = rsum[i];
    }
    __syncthreads();
#pragma unroll
    for (int i = 0; i < 4; ++i) {
        int r = quad * 4 + i;
        float tot = redsum[0][r] + redsum[1][r] + redsum[2][r] + redsum[3][r];
        float inv = 1.0f / tot;
        int row = m0 + r;
        _Float16* Prow = P + ((size_t)b * SEQ + row) * SEQ;
#pragma unroll
        for (int nt = 0; nt < 32; ++nt) {
            int ncol = nt * 64 + wave * 16 + l16;
            Prow[ncol] = (_Float16)(sc[nt][i] * inv);
        }
    }
}

// ---------------------------------------------------------------- PV: u <- u .* (P @ v)   (in place)
__global__ __launch_bounds__(256) void pv_kernel(
    const _Float16* __restrict__ P, const _Float16* __restrict__ vT,
    _Float16* __restrict__ u)
{
    __shared__ _Float16 smem[16384];
    TileCtx t = make_ctx();
    const int b = blockIdx.z;
    const int m0 = blockIdx.y * 128;
    const int n0 = blockIdx.x * 128;
    const _Float16* Pb  = P  + (size_t)b * SEQ * SEQ;
    const _Float16* vTb = vT + (size_t)b * INTER * SEQ;

    floatx4 acc[4][4] = {};
    gemm_mainloop_db(t, Pb + (size_t)m0 * SEQ, SEQ, vTb + (size_t)n0 * SEQ, SEQ, SEQ, smem, acc);

#pragma unroll
    for (int mt = 0; mt < 4; ++mt) {
#pragma unroll
        for (int nt = 0; nt < 4; ++nt) {
            int col = n0 + t.wn + nt * 16 + t.l16;
#pragma unroll
            for (int i = 0; i < 4; ++i) {
                int row = m0 + t.wm + mt * 16 + t.quad * 4 + i;
                size_t gidx = ((size_t)(b * SEQ + row)) * INTER + col;
                float uv = (float)u[gidx];
                u[gidx] = (_Float16)(acc[mt][nt][i] * uv);
            }
        }
    }
}

// ---------------------------------------------------------------- GEMM2: out = t @ Wo (fp32 out)
__global__ __launch_bounds__(256) void gemm2_kernel(
    const _Float16* __restrict__ tin, const _Float16* __restrict__ WoT,
    float* __restrict__ out)
{
    __shared__ _Float16 smem[16384];
    TileCtx t = make_ctx();
    const int m0 = blockIdx.y * 128;
    const int n0 = blockIdx.x * 128;

    floatx4 acc[4][4] = {};
    gemm_mainloop_db(t, tin + (size_t)m0 * INTER, INTER, WoT + (size_t)n0 * INTER, INTER, INTER, smem, acc);

#pragma unroll
    for (int mt = 0; mt < 4; ++mt) {
#pragma unroll
        for (int nt = 0; nt < 4; ++nt) {
            int col = n0 + t.wn + nt * 16 + t.l16;
#pragma unroll
            for (int i = 0; i < 4; ++i) {
                int row = m0 + t.wm + mt * 16 + t.quad * 4 + i;
                out[(size_t)row * HID + col] = acc[mt][nt][i];
            }
        }
    }
}

// ---------------------------------------------------------------- launch
extern "C" void kernel_launch(void* const* d_in, const int* in_sizes, int n_in,
                              void* d_out, int out_size, void* d_ws, size_t ws_size,
                              hipStream_t stream) {
    const float* H    = (const float*)d_in[0];
    const float* Wi   = (const float*)d_in[1];
    const float* Wo   = (const float*)d_in[2];
    const float* qg   = (const float*)d_in[3];
    const float* kg   = (const float*)d_in[4];
    const int*   mask = (const int*)d_in[5];
    float* out = (float*)d_out;

    char* base = (char*)d_ws;
    size_t off = 0;
    auto alloc = [&](size_t bytes) { void* p = base + off; off = (off + bytes + 255) & ~(size_t)255; return p; };
    _Float16* Hb   = (_Float16*)alloc((size_t)MROWS * HID * 2);
    _Float16* WiT  = (_Float16*)alloc((size_t)NTOT * HID * 2);
    _Float16* WoT  = (_Float16*)alloc((size_t)HID * INTER * 2);
    _Float16* u    = (_Float16*)alloc((size_t)MROWS * INTER * 2);   // becomes t in-place after pv
    _Float16* vT   = (_Float16*)alloc((size_t)BATCH * INTER * SEQ * 2);
    _Float16* q    = (_Float16*)alloc((size_t)MROWS * DK * 2);
    _Float16* k    = (_Float16*)alloc((size_t)MROWS * DK * 2);
    _Float16* P    = (_Float16*)alloc((size_t)BATCH * SEQ * SEQ * 2);
    float*    scales = (float*)alloc(4 * sizeof(float));

    {
        int n = MROWS * HID;
        cast_h_kernel<<<(n + 255) / 256, 256, 0, stream>>>(H, Hb, n);
        trans_wi_kernel<<<(HID * NTOT + 255) / 256, 256, 0, stream>>>(Wi, WiT);
        trans_wo_kernel<<<(INTER * HID + 255) / 256, 256, 0, stream>>>(Wo, WoT);
        mask_scales_kernel<<<BATCH, 256, 0, stream>>>(mask, scales);
    }
    // GEMM1: M=8192 N=3200 K=768
    {
        dim3 grid(NTOT / 128, MROWS / 128);
        gemm1_kernel<<<grid, 256, 0, stream>>>(Hb, WiT, qg, kg, u, vT, q, k);
    }
    // scores + softmax -> P
    {
        dim3 grid(SEQ / 16, BATCH);
        scores_kernel<<<grid, 256, 0, stream>>>(q, k, mask, scales, P);
    }
    // PV: per batch M=2048 N=1536 K=2048
    {
        dim3 grid(INTER / 128, SEQ / 128, BATCH);
        pv_kernel<<<grid, 256, 0, stream>>>(P, vT, u);
    }
    // GEMM2: M=8192 N=768 K=1536
    {
        dim3 grid(HID / 128, MROWS / 128);
        gemm2_kernel<<<grid, 256, 0, stream>>>(u, WoT, out);
    }
}

// Round 10
// 331.513 us; speedup vs baseline: 3.3198x; 1.0843x over previous
//
#include <hip/hip_runtime.h>
#include <hip/hip_bf16.h>
#include <math.h>

// Problem constants
#define BATCH 4
#define SEQ   2048
#define HID   768
#define INTER 1536
#define DK    128
#define NTOT  3200      // 2*INTER + DK
#define MROWS 8192      // BATCH*SEQ
#define LN512 6.2383246250395075f

typedef _Float16 half8  __attribute__((ext_vector_type(8)));
typedef float    floatx4 __attribute__((ext_vector_type(4)));

typedef const __attribute__((address_space(1))) unsigned int* gas1_t;
typedef __attribute__((address_space(3))) unsigned int* las3_t;

static __device__ __forceinline__ void load16(const _Float16* g, _Float16* l) {
    __builtin_amdgcn_global_load_lds((gas1_t)g, (las3_t)l, 16, 0, 0);
}
// Compiler-opaque barriers/waits: memory clobber pins IR ordering;
// hardware waits only the stated counts (no vmcnt(0) drain mid-loop).
#define WAIT_VM(N)    asm volatile("s_waitcnt vmcnt(" #N ")" ::: "memory")
#define WAIT_LGKM0()  asm volatile("s_waitcnt lgkmcnt(0)" ::: "memory")
#define BARRIER_RAW() asm volatile("s_barrier" ::: "memory")

// ---------------------------------------------------------------- prep kernels
__global__ void cast_h_kernel(const float* __restrict__ in, _Float16* __restrict__ out, int n) {
    int i = (blockIdx.x * blockDim.x + threadIdx.x) * 8;
    if (i < n) {
        float4 a = *reinterpret_cast<const float4*>(in + i);
        float4 b = *reinterpret_cast<const float4*>(in + i + 4);
        half8 h = {(_Float16)a.x, (_Float16)a.y, (_Float16)a.z, (_Float16)a.w,
                   (_Float16)b.x, (_Float16)b.y, (_Float16)b.z, (_Float16)b.w};
        *reinterpret_cast<half8*>(out + i) = h;
    }
}

// 32x32 LDS tile transpose, coalesced read + write.  WiT[c][r] = Wi[r][c]
__global__ void trans_wi_kernel(const float* __restrict__ Wi, _Float16* __restrict__ WiT) {
    __shared__ _Float16 tile[32][33];
    const int c0 = blockIdx.x * 32, r0 = blockIdx.y * 32;
    const int tx = threadIdx.x, ty = threadIdx.y;
#pragma unroll
    for (int j = 0; j < 32; j += 8)
        tile[tx][ty + j] = (_Float16)Wi[(size_t)(r0 + ty + j) * NTOT + c0 + tx];
    __syncthreads();
#pragma unroll
    for (int j = 0; j < 32; j += 8)
        WiT[(size_t)(c0 + ty + j) * HID + r0 + tx] = tile[ty + j][tx];
}

__global__ void trans_wo_kernel(const float* __restrict__ Wo, _Float16* __restrict__ WoT) {
    __shared__ _Float16 tile[32][33];
    const int c0 = blockIdx.x * 32, r0 = blockIdx.y * 32;
    const int tx = threadIdx.x, ty = threadIdx.y;
#pragma unroll
    for (int j = 0; j < 32; j += 8)
        tile[tx][ty + j] = (_Float16)Wo[(size_t)(r0 + ty + j) * HID + c0 + tx];
    __syncthreads();
#pragma unroll
    for (int j = 0; j < 32; j += 8)
        WoT[(size_t)(c0 + ty + j) * INTER + r0 + tx] = tile[ty + j][tx];
}

__global__ void mask_scales_kernel(const int* __restrict__ mask, float* __restrict__ scales) {
    __shared__ int sh[256];
    int b = blockIdx.x;
    int s = 0;
    for (int i = threadIdx.x; i < SEQ; i += 256) s += mask[b * SEQ + i];
    sh[threadIdx.x] = s;
    __syncthreads();
    for (int off = 128; off > 0; off >>= 1) {
        if (threadIdx.x < off) sh[threadIdx.x] += sh[threadIdx.x + off];
        __syncthreads();
    }
    if (threadIdx.x == 0) scales[b] = logf((float)sh[0]) / LN512;
}

// ---------------------------------------------------------------- tiled GEMM mainloop, 2-stage (proven R7)
// C(128x128) += A(128xK) * BT(128xK)^T. 256 thr = 4 waves 2x2; wave does 64x64.
// smem halves: A bufs [0,4096),[4096,8192); B bufs [8192,12288),[12288,16384).
// Pipeline: issue tile k+1 DMA into other buffer, wait vmcnt(4) (own tile-k loads
// landed), raw barrier, ds_read+MFMA, lgkmcnt(0), raw barrier.
struct TileCtx {
    int tid, wave, lane, quad, l16, wm, wn, c0, c1;
};
static __device__ __forceinline__ TileCtx make_ctx() {
    TileCtx t;
    t.tid = threadIdx.x;
    t.wave = t.tid >> 6; t.lane = t.tid & 63;
    t.quad = t.lane >> 4; t.l16 = t.lane & 15;
    t.wm = (t.wave & 1) * 64;
    t.wn = (t.wave >> 1) * 64;
    t.c0 = t.tid;
    t.c1 = t.tid + 256;
    return t;
}

static __device__ __forceinline__ void gemm_mainloop_db(
    const TileCtx& t,
    const _Float16* __restrict__ Ag, int lda,   // &A[m0][0]
    const _Float16* __restrict__ Bg, int ldb,   // &BT[n0][0]
    int K, _Float16* smem, floatx4 acc[4][4])
{
    const int ar0 = t.c0 >> 2, ak0 = (t.c0 & 3) * 8;
    const int ar1 = t.c1 >> 2, ak1 = (t.c1 & 3) * 8;
    const _Float16* a0 = Ag + (size_t)ar0 * lda + ak0;
    const _Float16* a1 = Ag + (size_t)ar1 * lda + ak1;
    const _Float16* b0 = Bg + (size_t)ar0 * ldb + ak0;
    const _Float16* b1 = Bg + (size_t)ar1 * ldb + ak1;
    _Float16* Asl = smem + t.c0 * 8;           // my A staging slot (buffer 0)
    _Float16* Bsl = smem + 8192 + t.c0 * 8;    // my B staging slot (buffer 0)

    // prologue: tile 0 -> buffer 0
    load16(a0, Asl);
    load16(a1, Asl + 2048);
    load16(b0, Bsl);
    load16(b1, Bsl + 2048);

    int buf = 0;
    for (int k0 = 0; k0 < K; k0 += 32) {
        if (k0 + 32 < K) {
            const int nb = (buf ^ 1) * 4096;
            load16(a0 + k0 + 32, Asl + nb);
            load16(a1 + k0 + 32, Asl + nb + 2048);
            load16(b0 + k0 + 32, Bsl + nb);
            load16(b1 + k0 + 32, Bsl + nb + 2048);
            WAIT_VM(4);    // my tile-k loads landed; 4 prefetches remain in flight
        } else {
            WAIT_VM(0);    // tail: drain
        }
        BARRIER_RAW();     // all waves' tile-k loads landed
        const _Float16* Ab = smem + buf * 4096;
        const _Float16* Bb = smem + 8192 + buf * 4096;
        half8 af[4], bf[4];
#pragma unroll
        for (int mt = 0; mt < 4; ++mt)
            af[mt] = *reinterpret_cast<const half8*>(Ab + (t.wm + mt * 16 + t.l16) * 32 + t.quad * 8);
#pragma unroll
        for (int nt = 0; nt < 4; ++nt)
            bf[nt] = *reinterpret_cast<const half8*>(Bb + (t.wn + nt * 16 + t.l16) * 32 + t.quad * 8);
#pragma unroll
        for (int mt = 0; mt < 4; ++mt)
#pragma unroll
            for (int nt = 0; nt < 4; ++nt)
                acc[mt][nt] = __builtin_amdgcn_mfma_f32_16x16x32_f16(af[mt], bf[nt], acc[mt][nt], 0, 0, 0);
        WAIT_LGKM0();      // pin ds_read completion inside this iteration (overwrite-race guard)
        BARRIER_RAW();     // all waves done reading buf
        buf ^= 1;
    }
}

// ---------------------------------------------------------------- GEMM1: silu(H@Wi) -> u, vT, q, k
// 1D grid 1600, XCD-banded: xcd=f%8 owns m-band [8*xcd,8*xcd+8); n slow within band.
__global__ __launch_bounds__(256) void gemm1_kernel(
    const _Float16* __restrict__ Hb, const _Float16* __restrict__ WiT,
    const float* __restrict__ qg, const float* __restrict__ kg,
    _Float16* __restrict__ u, _Float16* __restrict__ vT,
    _Float16* __restrict__ q, _Float16* __restrict__ k)
{
    __shared__ _Float16 smem[16384];
    TileCtx t = make_ctx();
    const int f = blockIdx.x;
    const int xcd = f & 7, i = f >> 3;          // i: 0..199
    const int m0 = ((xcd << 3) | (i & 7)) * 128;
    const int n0 = (i >> 3) * 128;              // 0..24

    floatx4 acc[4][4] = {};
    gemm_mainloop_db(t, Hb + (size_t)m0 * HID, HID, WiT + (size_t)n0 * HID, HID, HID, smem, acc);

    if (n0 >= INTER && n0 < 2 * INTER) {
        // vT path: transpose via LDS (XOR swizzle), then coalesced 16B stores.
        const int bb = m0 >> 11, sloc = m0 & (SEQ - 1), cI = n0 - INTER;
#pragma unroll
        for (int mt = 0; mt < 4; ++mt) {
#pragma unroll
            for (int nt = 0; nt < 4; ++nt) {
                int c = t.wn + nt * 16 + t.l16;
#pragma unroll
                for (int i2 = 0; i2 < 4; ++i2) {
                    int r = t.wm + mt * 16 + t.quad * 4 + i2;
                    float x = acc[mt][nt][i2];
                    float y = x / (1.0f + __expf(-x));   // silu
                    smem[c * 128 + (r ^ ((c & 15) << 3))] = (_Float16)y;
                }
            }
        }
        __syncthreads();
#pragma unroll
        for (int p = 0; p < 8; ++p) {
            int chunk = t.tid + p * 256;         // 2048 chunks of 8 halves
            int cl = chunk >> 4, sc = chunk & 15;
            int scs = sc ^ (cl & 15);
            half8 v = *reinterpret_cast<const half8*>(smem + cl * 128 + scs * 8);
            *reinterpret_cast<half8*>(vT + ((size_t)bb * INTER + cI + cl) * SEQ + sloc + sc * 8) = v;
        }
    } else {
#pragma unroll
        for (int mt = 0; mt < 4; ++mt) {
#pragma unroll
            for (int nt = 0; nt < 4; ++nt) {
                int col = n0 + t.wn + nt * 16 + t.l16;
#pragma unroll
                for (int i2 = 0; i2 < 4; ++i2) {
                    int row = m0 + t.wm + mt * 16 + t.quad * 4 + i2;
                    float x = acc[mt][nt][i2];
                    float y = x / (1.0f + __expf(-x));   // silu
                    if (n0 < INTER) {
                        u[(size_t)row * INTER + col] = (_Float16)y;
                    } else {
                        int c = col - 2 * INTER;
                        q[(size_t)row * DK + c] = (_Float16)(y * qg[c]);
                        k[(size_t)row * DK + c] = (_Float16)(y * kg[c]);
                    }
                }
            }
        }
    }
}

// ---------------------------------------------------------------- scores + softmax -> P (f16)
__global__ __launch_bounds__(256) void scores_kernel(
    const _Float16* __restrict__ q, const _Float16* __restrict__ k,
    const int* __restrict__ mask, const float* __restrict__ scales,
    _Float16* __restrict__ P)
{
    const int b = blockIdx.y;
    const int m0 = blockIdx.x * 16;
    const int tid = threadIdx.x;
    const int wave = tid >> 6, lane = tid & 63, quad = lane >> 4, l16 = lane & 15;
    const float scale = scales[b];

    half8 aq[4];
    const _Float16* qrow = q + (b * SEQ + m0 + l16) * DK + quad * 8;
#pragma unroll
    for (int kk = 0; kk < 4; ++kk) aq[kk] = *reinterpret_cast<const half8*>(qrow + kk * 32);

    floatx4 sc[32];
#pragma unroll
    for (int nt = 0; nt < 32; ++nt) {
        int n0 = nt * 64 + wave * 16;
        const _Float16* krow = k + (b * SEQ + n0 + l16) * DK + quad * 8;
        floatx4 acc = {};
#pragma unroll
        for (int kk = 0; kk < 4; ++kk) {
            half8 bq = *reinterpret_cast<const half8*>(krow + kk * 32);
            acc = __builtin_amdgcn_mfma_f32_16x16x32_f16(aq[kk], bq, acc, 0, 0, 0);
        }
        sc[nt] = acc;
    }

    const float rs = 0.08838834764831845f * scale;
    const float mval = -1e12f * scale;
    float rmax[4] = {-3.4e38f, -3.4e38f, -3.4e38f, -3.4e38f};
#pragma unroll
    for (int nt = 0; nt < 32; ++nt) {
        int ncol = nt * 64 + wave * 16 + l16;
        bool mok = mask[b * SEQ + ncol] != 0;
#pragma unroll
        for (int i = 0; i < 4; ++i) {
            float s = mok ? sc[nt][i] * rs : mval;
            sc[nt][i] = s;
            rmax[i] = fmaxf(rmax[i], s);
        }
    }
#pragma unroll
    for (int i = 0; i < 4; ++i) {
#pragma unroll
        for (int off = 1; off < 16; off <<= 1)
            rmax[i] = fmaxf(rmax[i], __shfl_xor(rmax[i], off, 64));
    }
    __shared__ float redmax[4][16];
    __shared__ float redsum[4][16];
    if (l16 == 0) {
#pragma unroll
        for (int i = 0; i < 4; ++i) redmax[wave][quad * 4 + i] = rmax[i];
    }
    __syncthreads();
#pragma unroll
    for (int i = 0; i < 4; ++i) {
        int r = quad * 4 + i;
        rmax[i] = fmaxf(fmaxf(redmax[0][r], redmax[1][r]), fmaxf(redmax[2][r], redmax[3][r]));
    }
    float rsum[4] = {0.f, 0.f, 0.f, 0.f};
#pragma unroll
    for (int nt = 0; nt < 32; ++nt) {
#pragma unroll
        for (int i = 0; i < 4; ++i) {
            float e = __expf(sc[nt][i] - rmax[i]);
            sc[nt][i] = e;
            rsum[i] += e;
        }
    }
#pragma unroll
    for (int i = 0; i < 4; ++i) {
#pragma unroll
        for (int off = 1; off < 16; off <<= 1) rsum[i] += __shfl_xor(rsum[i], off, 64);
    }
    if (l16 == 0) {
#pragma unroll
        for (int i = 0; i < 4; ++i) redsum[wave][quad * 4 + i] = rsum[i];
    }
    __syncthreads();
#pragma unroll
    for (int i = 0; i < 4; ++i) {
        int r = quad * 4 + i;
        float tot = redsum[0][r] + redsum[1][r] + redsum[2][r] + redsum[3][r];
        float inv = 1.0f / tot;
        int row = m0 + r;
        _Float16* Prow = P + ((size_t)b * SEQ + row) * SEQ;
#pragma unroll
        for (int nt = 0; nt < 32; ++nt) {
            int ncol = nt * 64 + wave * 16 + l16;
            Prow[ncol] = (_Float16)(sc[nt][i] * inv);
        }
    }
}

// ---------------------------------------------------------------- PV: u <- u .* (P @ v)   (in place)
// 1D grid 768: xcd=f%8, i=f/8 (0..95); batch=i/24; j=i%24; m=xcd*2+(j&1); n=j/2.
__global__ __launch_bounds__(256) void pv_kernel(
    const _Float16* __restrict__ P, const _Float16* __restrict__ vT,
    _Float16* __restrict__ u)
{
    __shared__ _Float16 smem[16384];
    TileCtx t = make_ctx();
    const int f = blockIdx.x;
    const int xcd = f & 7, i = f >> 3;          // i: 0..95
    const int b = i / 24, j = i % 24;
    const int m0 = (xcd * 2 + (j & 1)) * 128;
    const int n0 = (j >> 1) * 128;
    const _Float16* Pb  = P  + (size_t)b * SEQ * SEQ;
    const _Float16* vTb = vT + (size_t)b * INTER * SEQ;

    floatx4 acc[4][4] = {};
    gemm_mainloop_db(t, Pb + (size_t)m0 * SEQ, SEQ, vTb + (size_t)n0 * SEQ, SEQ, SEQ, smem, acc);

#pragma unroll
    for (int mt = 0; mt < 4; ++mt) {
#pragma unroll
        for (int nt = 0; nt < 4; ++nt) {
            int col = n0 + t.wn + nt * 16 + t.l16;
#pragma unroll
            for (int i2 = 0; i2 < 4; ++i2) {
                int row = m0 + t.wm + mt * 16 + t.quad * 4 + i2;
                size_t gidx = ((size_t)(b * SEQ + row)) * INTER + col;
                float uv = (float)u[gidx];
                u[gidx] = (_Float16)(acc[mt][nt][i2] * uv);
            }
        }
    }
}

// ---------------------------------------------------------------- GEMM2: out = t @ Wo (fp32 out)
// 1D grid 384: xcd=f%8, i=f/8 (0..47); m=xcd*8+(i&7); n=i>>3 (0..5).
__global__ __launch_bounds__(256) void gemm2_kernel(
    const _Float16* __restrict__ tin, const _Float16* __restrict__ WoT,
    float* __restrict__ out)
{
    __shared__ _Float16 smem[16384];
    TileCtx t = make_ctx();
    const int f = blockIdx.x;
    const int xcd = f & 7, i = f >> 3;          // i: 0..47
    const int m0 = ((xcd << 3) | (i & 7)) * 128;
    const int n0 = (i >> 3) * 128;              // 0..5

    floatx4 acc[4][4] = {};
    gemm_mainloop_db(t, tin + (size_t)m0 * INTER, INTER, WoT + (size_t)n0 * INTER, INTER, INTER, smem, acc);

#pragma unroll
    for (int mt = 0; mt < 4; ++mt) {
#pragma unroll
        for (int nt = 0; nt < 4; ++nt) {
            int col = n0 + t.wn + nt * 16 + t.l16;
#pragma unroll
            for (int i2 = 0; i2 < 4; ++i2) {
                int row = m0 + t.wm + mt * 16 + t.quad * 4 + i2;
                out[(size_t)row * HID + col] = acc[mt][nt][i2];
            }
        }
    }
}

// ---------------------------------------------------------------- launch
extern "C" void kernel_launch(void* const* d_in, const int* in_sizes, int n_in,
                              void* d_out, int out_size, void* d_ws, size_t ws_size,
                              hipStream_t stream) {
    const float* H    = (const float*)d_in[0];
    const float* Wi   = (const float*)d_in[1];
    const float* Wo   = (const float*)d_in[2];
    const float* qg   = (const float*)d_in[3];
    const float* kg   = (const float*)d_in[4];
    const int*   mask = (const int*)d_in[5];
    float* out = (float*)d_out;

    char* base = (char*)d_ws;
    size_t off = 0;
    auto alloc = [&](size_t bytes) { void* p = base + off; off = (off + bytes + 255) & ~(size_t)255; return p; };
    _Float16* Hb   = (_Float16*)alloc((size_t)MROWS * HID * 2);
    _Float16* WiT  = (_Float16*)alloc((size_t)NTOT * HID * 2);
    _Float16* WoT  = (_Float16*)alloc((size_t)HID * INTER * 2);
    _Float16* u    = (_Float16*)alloc((size_t)MROWS * INTER * 2);   // becomes t in-place after pv
    _Float16* vT   = (_Float16*)alloc((size_t)BATCH * INTER * SEQ * 2);
    _Float16* q    = (_Float16*)alloc((size_t)MROWS * DK * 2);
    _Float16* k    = (_Float16*)alloc((size_t)MROWS * DK * 2);
    _Float16* P    = (_Float16*)alloc((size_t)BATCH * SEQ * SEQ * 2);
    float*    scales = (float*)alloc(4 * sizeof(float));

    {
        int n = MROWS * HID;
        cast_h_kernel<<<n / 8 / 256, 256, 0, stream>>>(H, Hb, n);
        trans_wi_kernel<<<dim3(NTOT / 32, HID / 32), dim3(32, 8), 0, stream>>>(Wi, WiT);
        trans_wo_kernel<<<dim3(HID / 32, INTER / 32), dim3(32, 8), 0, stream>>>(Wo, WoT);
        mask_scales_kernel<<<BATCH, 256, 0, stream>>>(mask, scales);
    }
    // GEMM1: M=8192 N=3200 K=768
    gemm1_kernel<<<1600, 256, 0, stream>>>(Hb, WiT, qg, kg, u, vT, q, k);
    // scores + softmax -> P
    {
        dim3 grid(SEQ / 16, BATCH);
        scores_kernel<<<grid, 256, 0, stream>>>(q, k, mask, scales, P);
    }
    // PV: per batch M=2048 N=1536 K=2048
    pv_kernel<<<768, 256, 0, stream>>>(P, vT, u);
    // GEMM2: M=8192 N=768 K=1536
    gemm2_kernel<<<384, 256, 0, stream>>>(u, WoT, out);
}

// Round 11
// 323.739 us; speedup vs baseline: 3.3995x; 1.0240x over previous
//
#include <hip/hip_runtime.h>
#include <hip/hip_bf16.h>
#include <math.h>

// Problem constants
#define BATCH 4
#define SEQ   2048
#define HID   768
#define INTER 1536
#define DK    128
#define NTOT  3200      // 2*INTER + DK
#define MROWS 8192      // BATCH*SEQ
#define LN512 6.2383246250395075f

typedef _Float16 half8  __attribute__((ext_vector_type(8)));
typedef float    floatx4 __attribute__((ext_vector_type(4)));

typedef const __attribute__((address_space(1))) unsigned int* gas1_t;
typedef __attribute__((address_space(3))) unsigned int* las3_t;

static __device__ __forceinline__ void load16(const _Float16* g, _Float16* l) {
    __builtin_amdgcn_global_load_lds((gas1_t)g, (las3_t)l, 16, 0, 0);
}
// Compiler-opaque barriers/waits: memory clobber pins IR ordering;
// hardware waits only the stated counts (no vmcnt(0) drain mid-loop).
#define WAIT_VM(N)    asm volatile("s_waitcnt vmcnt(" #N ")" ::: "memory")
#define WAIT_LGKM0()  asm volatile("s_waitcnt lgkmcnt(0)" ::: "memory")
#define BARRIER_RAW() asm volatile("s_barrier" ::: "memory")

// ---------------------------------------------------------------- prep kernels
__global__ void cast_h_kernel(const float* __restrict__ in, _Float16* __restrict__ out, int n) {
    int i = (blockIdx.x * blockDim.x + threadIdx.x) * 8;
    if (i < n) {
        float4 a = *reinterpret_cast<const float4*>(in + i);
        float4 b = *reinterpret_cast<const float4*>(in + i + 4);
        half8 h = {(_Float16)a.x, (_Float16)a.y, (_Float16)a.z, (_Float16)a.w,
                   (_Float16)b.x, (_Float16)b.y, (_Float16)b.z, (_Float16)b.w};
        *reinterpret_cast<half8*>(out + i) = h;
    }
}

// 32x32 LDS tile transpose, coalesced read + write.  WiT[c][r] = Wi[r][c]
__global__ void trans_wi_kernel(const float* __restrict__ Wi, _Float16* __restrict__ WiT) {
    __shared__ _Float16 tile[32][33];
    const int c0 = blockIdx.x * 32, r0 = blockIdx.y * 32;
    const int tx = threadIdx.x, ty = threadIdx.y;
#pragma unroll
    for (int j = 0; j < 32; j += 8)
        tile[tx][ty + j] = (_Float16)Wi[(size_t)(r0 + ty + j) * NTOT + c0 + tx];
    __syncthreads();
#pragma unroll
    for (int j = 0; j < 32; j += 8)
        WiT[(size_t)(c0 + ty + j) * HID + r0 + tx] = tile[ty + j][tx];
}

__global__ void trans_wo_kernel(const float* __restrict__ Wo, _Float16* __restrict__ WoT) {
    __shared__ _Float16 tile[32][33];
    const int c0 = blockIdx.x * 32, r0 = blockIdx.y * 32;
    const int tx = threadIdx.x, ty = threadIdx.y;
#pragma unroll
    for (int j = 0; j < 32; j += 8)
        tile[tx][ty + j] = (_Float16)Wo[(size_t)(r0 + ty + j) * HID + c0 + tx];
    __syncthreads();
#pragma unroll
    for (int j = 0; j < 32; j += 8)
        WoT[(size_t)(c0 + ty + j) * INTER + r0 + tx] = tile[ty + j][tx];
}

__global__ void mask_scales_kernel(const int* __restrict__ mask, float* __restrict__ scales) {
    __shared__ int sh[256];
    int b = blockIdx.x;
    int s = 0;
    for (int i = threadIdx.x; i < SEQ; i += 256) s += mask[b * SEQ + i];
    sh[threadIdx.x] = s;
    __syncthreads();
    for (int off = 128; off > 0; off >>= 1) {
        if (threadIdx.x < off) sh[threadIdx.x] += sh[threadIdx.x + off];
        __syncthreads();
    }
    if (threadIdx.x == 0) scales[b] = logf((float)sh[0]) / LN512;
}

// ---------------------------------------------------------------- tiled GEMM mainloop, 2-stage, bank-swizzled LDS
// C(128x128) += A(128xK) * BT(128xK)^T. 256 thr = 4 waves 2x2; wave does 64x64.
// LDS tile layout: slot for (row, kc) = row*4 + (kc ^ ((row>>1)&3)), 16B slots.
// The swizzle spreads each quad's 16 fragment-read lanes over 8 bank groups
// (was 2 groups = 8-way conflict = the R10 bottleneck). DMA side: lane chunk c
// fetches global kc = (c&3)^((c>>3)&3) — a permutation within the same 64B row,
// so global coalescing is unchanged.
struct TileCtx {
    int tid, wave, lane, quad, l16, wm, wn, c0, c1, sw;
};
static __device__ __forceinline__ TileCtx make_ctx() {
    TileCtx t;
    t.tid = threadIdx.x;
    t.wave = t.tid >> 6; t.lane = t.tid & 63;
    t.quad = t.lane >> 4; t.l16 = t.lane & 15;
    t.wm = (t.wave & 1) * 64;
    t.wn = (t.wave >> 1) * 64;
    t.c0 = t.tid;
    t.c1 = t.tid + 256;
    t.sw = (t.l16 >> 1) & 3;     // fragment-read swizzle: (row>>1)&3 == (l16>>1)&3 (row = mult16 + l16)
    return t;
}

static __device__ __forceinline__ void gemm_mainloop_db(
    const TileCtx& t,
    const _Float16* __restrict__ Ag, int lda,   // &A[m0][0]
    const _Float16* __restrict__ Bg, int ldb,   // &BT[n0][0]
    int K, _Float16* smem, floatx4 acc[4][4])
{
    const int ar0 = t.c0 >> 2, ak0 = ((t.c0 & 3) ^ ((t.c0 >> 3) & 3)) * 8;
    const int ar1 = t.c1 >> 2, ak1 = ((t.c1 & 3) ^ ((t.c1 >> 3) & 3)) * 8;
    const _Float16* a0 = Ag + (size_t)ar0 * lda + ak0;
    const _Float16* a1 = Ag + (size_t)ar1 * lda + ak1;
    const _Float16* b0 = Bg + (size_t)ar0 * ldb + ak0;
    const _Float16* b1 = Bg + (size_t)ar1 * ldb + ak1;
    _Float16* Asl = smem + t.c0 * 8;           // my A staging slot (buffer 0)
    _Float16* Bsl = smem + 8192 + t.c0 * 8;    // my B staging slot (buffer 0)

    // fragment read offsets (element units): row*32 + (quad ^ sw)*8
    const int qsw = (t.quad ^ t.sw) * 8;

    // prologue: tile 0 -> buffer 0
    load16(a0, Asl);
    load16(a1, Asl + 2048);
    load16(b0, Bsl);
    load16(b1, Bsl + 2048);

    int buf = 0;
    for (int k0 = 0; k0 < K; k0 += 32) {
        if (k0 + 32 < K) {
            const int nb = (buf ^ 1) * 4096;
            load16(a0 + k0 + 32, Asl + nb);
            load16(a1 + k0 + 32, Asl + nb + 2048);
            load16(b0 + k0 + 32, Bsl + nb);
            load16(b1 + k0 + 32, Bsl + nb + 2048);
            WAIT_VM(4);    // my tile-k loads landed; 4 prefetches remain in flight
        } else {
            WAIT_VM(0);    // tail: drain
        }
        BARRIER_RAW();     // all waves' tile-k loads landed
        const _Float16* Ab = smem + buf * 4096;
        const _Float16* Bb = smem + 8192 + buf * 4096;
        half8 af[4], bf[4];
#pragma unroll
        for (int mt = 0; mt < 4; ++mt)
            af[mt] = *reinterpret_cast<const half8*>(Ab + (t.wm + mt * 16 + t.l16) * 32 + qsw);
#pragma unroll
        for (int nt = 0; nt < 4; ++nt)
            bf[nt] = *reinterpret_cast<const half8*>(Bb + (t.wn + nt * 16 + t.l16) * 32 + qsw);
#pragma unroll
        for (int mt = 0; mt < 4; ++mt)
#pragma unroll
            for (int nt = 0; nt < 4; ++nt)
                acc[mt][nt] = __builtin_amdgcn_mfma_f32_16x16x32_f16(af[mt], bf[nt], acc[mt][nt], 0, 0, 0);
        WAIT_LGKM0();      // pin ds_read completion inside this iteration (overwrite-race guard)
        BARRIER_RAW();     // all waves done reading buf
        buf ^= 1;
    }
}

// ---------------------------------------------------------------- GEMM1: silu(H@Wi) -> u, vT, q, k
// 1D grid 1600, XCD-banded: xcd=f%8 owns m-band [8*xcd,8*xcd+8); n slow within band.
__global__ __launch_bounds__(256) void gemm1_kernel(
    const _Float16* __restrict__ Hb, const _Float16* __restrict__ WiT,
    const float* __restrict__ qg, const float* __restrict__ kg,
    _Float16* __restrict__ u, _Float16* __restrict__ vT,
    _Float16* __restrict__ q, _Float16* __restrict__ k)
{
    __shared__ _Float16 smem[16384];
    TileCtx t = make_ctx();
    const int f = blockIdx.x;
    const int xcd = f & 7, i = f >> 3;          // i: 0..199
    const int m0 = ((xcd << 3) | (i & 7)) * 128;
    const int n0 = (i >> 3) * 128;              // 0..24

    floatx4 acc[4][4] = {};
    gemm_mainloop_db(t, Hb + (size_t)m0 * HID, HID, WiT + (size_t)n0 * HID, HID, HID, smem, acc);

    if (n0 >= INTER && n0 < 2 * INTER) {
        // vT path: transpose via LDS (XOR swizzle), then coalesced 16B stores.
        const int bb = m0 >> 11, sloc = m0 & (SEQ - 1), cI = n0 - INTER;
#pragma unroll
        for (int mt = 0; mt < 4; ++mt) {
#pragma unroll
            for (int nt = 0; nt < 4; ++nt) {
                int c = t.wn + nt * 16 + t.l16;
#pragma unroll
                for (int i2 = 0; i2 < 4; ++i2) {
                    int r = t.wm + mt * 16 + t.quad * 4 + i2;
                    float x = acc[mt][nt][i2];
                    float y = x / (1.0f + __expf(-x));   // silu
                    smem[c * 128 + (r ^ ((c & 15) << 3))] = (_Float16)y;
                }
            }
        }
        __syncthreads();
#pragma unroll
        for (int p = 0; p < 8; ++p) {
            int chunk = t.tid + p * 256;         // 2048 chunks of 8 halves
            int cl = chunk >> 4, sc = chunk & 15;
            int scs = sc ^ (cl & 15);
            half8 v = *reinterpret_cast<const half8*>(smem + cl * 128 + scs * 8);
            *reinterpret_cast<half8*>(vT + ((size_t)bb * INTER + cI + cl) * SEQ + sloc + sc * 8) = v;
        }
    } else {
#pragma unroll
        for (int mt = 0; mt < 4; ++mt) {
#pragma unroll
            for (int nt = 0; nt < 4; ++nt) {
                int col = n0 + t.wn + nt * 16 + t.l16;
#pragma unroll
                for (int i2 = 0; i2 < 4; ++i2) {
                    int row = m0 + t.wm + mt * 16 + t.quad * 4 + i2;
                    float x = acc[mt][nt][i2];
                    float y = x / (1.0f + __expf(-x));   // silu
                    if (n0 < INTER) {
                        u[(size_t)row * INTER + col] = (_Float16)y;
                    } else {
                        int c = col - 2 * INTER;
                        q[(size_t)row * DK + c] = (_Float16)(y * qg[c]);
                        k[(size_t)row * DK + c] = (_Float16)(y * kg[c]);
                    }
                }
            }
        }
    }
}

// ---------------------------------------------------------------- scores + softmax -> P (f16)
__global__ __launch_bounds__(256) void scores_kernel(
    const _Float16* __restrict__ q, const _Float16* __restrict__ k,
    const int* __restrict__ mask, const float* __restrict__ scales,
    _Float16* __restrict__ P)
{
    const int b = blockIdx.y;
    const int m0 = blockIdx.x * 16;
    const int tid = threadIdx.x;
    const int wave = tid >> 6, lane = tid & 63, quad = lane >> 4, l16 = lane & 15;
    const float scale = scales[b];

    half8 aq[4];
    const _Float16* qrow = q + (b * SEQ + m0 + l16) * DK + quad * 8;
#pragma unroll
    for (int kk = 0; kk < 4; ++kk) aq[kk] = *reinterpret_cast<const half8*>(qrow + kk * 32);

    floatx4 sc[32];
#pragma unroll
    for (int nt = 0; nt < 32; ++nt) {
        int n0 = nt * 64 + wave * 16;
        const _Float16* krow = k + (b * SEQ + n0 + l16) * DK + quad * 8;
        floatx4 acc = {};
#pragma unroll
        for (int kk = 0; kk < 4; ++kk) {
            half8 bq = *reinterpret_cast<const half8*>(krow + kk * 32);
            acc = __builtin_amdgcn_mfma_f32_16x16x32_f16(aq[kk], bq, acc, 0, 0, 0);
        }
        sc[nt] = acc;
    }

    const float rs = 0.08838834764831845f * scale;
    const float mval = -1e12f * scale;
    float rmax[4] = {-3.4e38f, -3.4e38f, -3.4e38f, -3.4e38f};
#pragma unroll
    for (int nt = 0; nt < 32; ++nt) {
        int ncol = nt * 64 + wave * 16 + l16;
        bool mok = mask[b * SEQ + ncol] != 0;
#pragma unroll
        for (int i = 0; i < 4; ++i) {
            float s = mok ? sc[nt][i] * rs : mval;
            sc[nt][i] = s;
            rmax[i] = fmaxf(rmax[i], s);
        }
    }
#pragma unroll
    for (int i = 0; i < 4; ++i) {
#pragma unroll
        for (int off = 1; off < 16; off <<= 1)
            rmax[i] = fmaxf(rmax[i], __shfl_xor(rmax[i], off, 64));
    }
    __shared__ float redmax[4][16];
    __shared__ float redsum[4][16];
    if (l16 == 0) {
#pragma unroll
        for (int i = 0; i < 4; ++i) redmax[wave][quad * 4 + i] = rmax[i];
    }
    __syncthreads();
#pragma unroll
    for (int i = 0; i < 4; ++i) {
        int r = quad * 4 + i;
        rmax[i] = fmaxf(fmaxf(redmax[0][r], redmax[1][r]), fmaxf(redmax[2][r], redmax[3][r]));
    }
    float rsum[4] = {0.f, 0.f, 0.f, 0.f};
#pragma unroll
    for (int nt = 0; nt < 32; ++nt) {
#pragma unroll
        for (int i = 0; i < 4; ++i) {
            float e = __expf(sc[nt][i] - rmax[i]);
            sc[nt][i] = e;
            rsum[i] += e;
        }
    }
#pragma unroll
    for (int i = 0; i < 4; ++i) {
#pragma unroll
        for (int off = 1; off < 16; off <<= 1) rsum[i] += __shfl_xor(rsum[i], off, 64);
    }
    if (l16 == 0) {
#pragma unroll
        for (int i = 0; i < 4; ++i) redsum[wave][quad * 4 + i] = rsum[i];
    }
    __syncthreads();
#pragma unroll
    for (int i = 0; i < 4; ++i) {
        int r = quad * 4 + i;
        float tot = redsum[0][r] + redsum[1][r] + redsum[2][r] + redsum[3][r];
        float inv = 1.0f / tot;
        int row = m0 + r;
        _Float16* Prow = P + ((size_t)b * SEQ + row) * SEQ;
#pragma unroll
        for (int nt = 0; nt < 32; ++nt) {
            int ncol = nt * 64 + wave * 16 + l16;
            Prow[ncol] = (_Float16)(sc[nt][i] * inv);
        }
    }
}

// ---------------------------------------------------------------- PV: u <- u .* (P @ v)   (in place)
// 1D grid 768: xcd=f%8, i=f/8 (0..95); batch=i/24; j=i%24; m=xcd*2+(j&1); n=j/2.
__global__ __launch_bounds__(256) void pv_kernel(
    const _Float16* __restrict__ P, const _Float16* __restrict__ vT,
    _Float16* __restrict__ u)
{
    __shared__ _Float16 smem[16384];
    TileCtx t = make_ctx();
    const int f = blockIdx.x;
    const int xcd = f & 7, i = f >> 3;          // i: 0..95
    const int b = i / 24, j = i % 24;
    const int m0 = (xcd * 2 + (j & 1)) * 128;
    const int n0 = (j >> 1) * 128;
    const _Float16* Pb  = P  + (size_t)b * SEQ * SEQ;
    const _Float16* vTb = vT + (size_t)b * INTER * SEQ;

    floatx4 acc[4][4] = {};
    gemm_mainloop_db(t, Pb + (size_t)m0 * SEQ, SEQ, vTb + (size_t)n0 * SEQ, SEQ, SEQ, smem, acc);

#pragma unroll
    for (int mt = 0; mt < 4; ++mt) {
#pragma unroll
        for (int nt = 0; nt < 4; ++nt) {
            int col = n0 + t.wn + nt * 16 + t.l16;
#pragma unroll
            for (int i2 = 0; i2 < 4; ++i2) {
                int row = m0 + t.wm + mt * 16 + t.quad * 4 + i2;
                size_t gidx = ((size_t)(b * SEQ + row)) * INTER + col;
                float uv = (float)u[gidx];
                u[gidx] = (_Float16)(acc[mt][nt][i2] * uv);
            }
        }
    }
}

// ---------------------------------------------------------------- GEMM2: out = t @ Wo (fp32 out)
// 1D grid 384: xcd=f%8, i=f/8 (0..47); m=xcd*8+(i&7); n=i>>3 (0..5).
__global__ __launch_bounds__(256) void gemm2_kernel(
    const _Float16* __restrict__ tin, const _Float16* __restrict__ WoT,
    float* __restrict__ out)
{
    __shared__ _Float16 smem[16384];
    TileCtx t = make_ctx();
    const int f = blockIdx.x;
    const int xcd = f & 7, i = f >> 3;          // i: 0..47
    const int m0 = ((xcd << 3) | (i & 7)) * 128;
    const int n0 = (i >> 3) * 128;              // 0..5

    floatx4 acc[4][4] = {};
    gemm_mainloop_db(t, tin + (size_t)m0 * INTER, INTER, WoT + (size_t)n0 * INTER, INTER, INTER, smem, acc);

#pragma unroll
    for (int mt = 0; mt < 4; ++mt) {
#pragma unroll
        for (int nt = 0; nt < 4; ++nt) {
            int col = n0 + t.wn + nt * 16 + t.l16;
#pragma unroll
            for (int i2 = 0; i2 < 4; ++i2) {
                int row = m0 + t.wm + mt * 16 + t.quad * 4 + i2;
                out[(size_t)row * HID + col] = acc[mt][nt][i2];
            }
        }
    }
}

// ---------------------------------------------------------------- launch
extern "C" void kernel_launch(void* const* d_in, const int* in_sizes, int n_in,
                              void* d_out, int out_size, void* d_ws, size_t ws_size,
                              hipStream_t stream) {
    const float* H    = (const float*)d_in[0];
    const float* Wi   = (const float*)d_in[1];
    const float* Wo   = (const float*)d_in[2];
    const float* qg   = (const float*)d_in[3];
    const float* kg   = (const float*)d_in[4];
    const int*   mask = (const int*)d_in[5];
    float* out = (float*)d_out;

    char* base = (char*)d_ws;
    size_t off = 0;
    auto alloc = [&](size_t bytes) { void* p = base + off; off = (off + bytes + 255) & ~(size_t)255; return p; };
    _Float16* Hb   = (_Float16*)alloc((size_t)MROWS * HID * 2);
    _Float16* WiT  = (_Float16*)alloc((size_t)NTOT * HID * 2);
    _Float16* WoT  = (_Float16*)alloc((size_t)HID * INTER * 2);
    _Float16* u    = (_Float16*)alloc((size_t)MROWS * INTER * 2);   // becomes t in-place after pv
    _Float16* vT   = (_Float16*)alloc((size_t)BATCH * INTER * SEQ * 2);
    _Float16* q    = (_Float16*)alloc((size_t)MROWS * DK * 2);
    _Float16* k    = (_Float16*)alloc((size_t)MROWS * DK * 2);
    _Float16* P    = (_Float16*)alloc((size_t)BATCH * SEQ * SEQ * 2);
    float*    scales = (float*)alloc(4 * sizeof(float));

    {
        int n = MROWS * HID;
        cast_h_kernel<<<n / 8 / 256, 256, 0, stream>>>(H, Hb, n);
        trans_wi_kernel<<<dim3(NTOT / 32, HID / 32), dim3(32, 8), 0, stream>>>(Wi, WiT);
        trans_wo_kernel<<<dim3(HID / 32, INTER / 32), dim3(32, 8), 0, stream>>>(Wo, WoT);
        mask_scales_kernel<<<BATCH, 256, 0, stream>>>(mask, scales);
    }
    // GEMM1: M=8192 N=3200 K=768
    gemm1_kernel<<<1600, 256, 0, stream>>>(Hb, WiT, qg, kg, u, vT, q, k);
    // scores + softmax -> P
    {
        dim3 grid(SEQ / 16, BATCH);
        scores_kernel<<<grid, 256, 0, stream>>>(q, k, mask, scales, P);
    }
    // PV: per batch M=2048 N=1536 K=2048
    pv_kernel<<<768, 256, 0, stream>>>(P, vT, u);
    // GEMM2: M=8192 N=768 K=1536
    gemm2_kernel<<<384, 256, 0, stream>>>(u, WoT, out);
}

// Round 12
// 310.808 us; speedup vs baseline: 3.5410x; 1.0416x over previous
//
#include <hip/hip_runtime.h>
#include <hip/hip_bf16.h>
#include <math.h>

// Problem constants
#define BATCH 4
#define SEQ   2048
#define HID   768
#define INTER 1536
#define DK    128
#define NTOT  3200      // 2*INTER + DK
#define MROWS 8192      // BATCH*SEQ
#define LN512 6.2383246250395075f

typedef _Float16 half8  __attribute__((ext_vector_type(8)));
typedef float    floatx4 __attribute__((ext_vector_type(4)));

typedef const __attribute__((address_space(1))) unsigned int* gas1_t;
typedef __attribute__((address_space(3))) unsigned int* las3_t;

static __device__ __forceinline__ void load16(const _Float16* g, _Float16* l) {
    __builtin_amdgcn_global_load_lds((gas1_t)g, (las3_t)l, 16, 0, 0);
}
// Compiler-opaque barriers/waits: memory clobber pins IR ordering;
// hardware waits only the stated counts (no vmcnt(0) drain mid-loop).
#define WAIT_VM(N)    asm volatile("s_waitcnt vmcnt(" #N ")" ::: "memory")
#define WAIT_LGKM0()  asm volatile("s_waitcnt lgkmcnt(0)" ::: "memory")
#define BARRIER_RAW() asm volatile("s_barrier" ::: "memory")

// ---------------------------------------------------------------- prep kernels
__global__ void cast_h_kernel(const float* __restrict__ in, _Float16* __restrict__ out, int n) {
    int i = (blockIdx.x * blockDim.x + threadIdx.x) * 8;
    if (i < n) {
        float4 a = *reinterpret_cast<const float4*>(in + i);
        float4 b = *reinterpret_cast<const float4*>(in + i + 4);
        half8 h = {(_Float16)a.x, (_Float16)a.y, (_Float16)a.z, (_Float16)a.w,
                   (_Float16)b.x, (_Float16)b.y, (_Float16)b.z, (_Float16)b.w};
        *reinterpret_cast<half8*>(out + i) = h;
    }
}

// 32x32 LDS tile transpose, coalesced read + write.  WiT[c][r] = Wi[r][c]
__global__ void trans_wi_kernel(const float* __restrict__ Wi, _Float16* __restrict__ WiT) {
    __shared__ _Float16 tile[32][33];
    const int c0 = blockIdx.x * 32, r0 = blockIdx.y * 32;
    const int tx = threadIdx.x, ty = threadIdx.y;
#pragma unroll
    for (int j = 0; j < 32; j += 8)
        tile[tx][ty + j] = (_Float16)Wi[(size_t)(r0 + ty + j) * NTOT + c0 + tx];
    __syncthreads();
#pragma unroll
    for (int j = 0; j < 32; j += 8)
        WiT[(size_t)(c0 + ty + j) * HID + r0 + tx] = tile[ty + j][tx];
}

__global__ void trans_wo_kernel(const float* __restrict__ Wo, _Float16* __restrict__ WoT) {
    __shared__ _Float16 tile[32][33];
    const int c0 = blockIdx.x * 32, r0 = blockIdx.y * 32;
    const int tx = threadIdx.x, ty = threadIdx.y;
#pragma unroll
    for (int j = 0; j < 32; j += 8)
        tile[tx][ty + j] = (_Float16)Wo[(size_t)(r0 + ty + j) * HID + c0 + tx];
    __syncthreads();
#pragma unroll
    for (int j = 0; j < 32; j += 8)
        WoT[(size_t)(c0 + ty + j) * INTER + r0 + tx] = tile[ty + j][tx];
}

__global__ void mask_scales_kernel(const int* __restrict__ mask, float* __restrict__ scales) {
    __shared__ int sh[256];
    int b = blockIdx.x;
    int s = 0;
    for (int i = threadIdx.x; i < SEQ; i += 256) s += mask[b * SEQ + i];
    sh[threadIdx.x] = s;
    __syncthreads();
    for (int off = 128; off > 0; off >>= 1) {
        if (threadIdx.x < off) sh[threadIdx.x] += sh[threadIdx.x + off];
        __syncthreads();
    }
    if (threadIdx.x == 0) scales[b] = logf((float)sh[0]) / LN512;
}

// ---------------------------------------------------------------- tiled GEMM mainloop
// 3-slot pipeline, ONE barrier per iteration, bank-swizzled LDS.
// C(128x128) += A(128xK) * BT(128xK)^T. 256 thr = 4 waves 2x2; wave does 64x64.
// Slots: A at smem+slot*4096, B at smem+12288+slot*4096 (halves), 48KB total.
// Per iter k: wait vmcnt(4) [tile-k landed; tile k+1 in flight] -> barrier ->
//   issue DMA tile k+2 into slot (k+2)%3 [== slot consumed at k-1; its reads
//   were lgkm-pinned before this barrier] -> ds_read slot k%3 + MFMA -> lgkm-pin.
// R8's race was issuing the DMA BEFORE the barrier; order fixed here.
struct TileCtx {
    int tid, wave, lane, quad, l16, wm, wn, c0, c1, sw;
};
static __device__ __forceinline__ TileCtx make_ctx() {
    TileCtx t;
    t.tid = threadIdx.x;
    t.wave = t.tid >> 6; t.lane = t.tid & 63;
    t.quad = t.lane >> 4; t.l16 = t.lane & 15;
    t.wm = (t.wave & 1) * 64;
    t.wn = (t.wave >> 1) * 64;
    t.c0 = t.tid;
    t.c1 = t.tid + 256;
    t.sw = (t.l16 >> 1) & 3;     // bank swizzle key (row>>1)&3
    return t;
}

static __device__ __forceinline__ void gemm_mainloop_3s(
    const TileCtx& t,
    const _Float16* __restrict__ Ag, int lda,   // &A[m0][0]
    const _Float16* __restrict__ Bg, int ldb,   // &BT[n0][0]
    int K, _Float16* smem, floatx4 acc[4][4])
{
    const int ar0 = t.c0 >> 2, ak0 = ((t.c0 & 3) ^ ((t.c0 >> 3) & 3)) * 8;
    const int ar1 = t.c1 >> 2, ak1 = ((t.c1 & 3) ^ ((t.c1 >> 3) & 3)) * 8;
    const _Float16* a0 = Ag + (size_t)ar0 * lda + ak0;
    const _Float16* a1 = Ag + (size_t)ar1 * lda + ak1;
    const _Float16* b0 = Bg + (size_t)ar0 * ldb + ak0;
    const _Float16* b1 = Bg + (size_t)ar1 * ldb + ak1;
    _Float16* Asl = smem + t.c0 * 8;            // my A staging slot base (slot 0)
    _Float16* Bsl = smem + 12288 + t.c0 * 8;    // my B staging slot base (slot 0)
    const int nIter = K >> 5;

    // fragment read offsets (element units): row*32 + (quad ^ sw)*8
    const int qsw = (t.quad ^ t.sw) * 8;

    // prologue: tile 0 -> slot 0, tile 1 -> slot 1
    load16(a0, Asl);        load16(a1, Asl + 2048);
    load16(b0, Bsl);        load16(b1, Bsl + 2048);
    if (nIter > 1) {
        load16(a0 + 32, Asl + 4096); load16(a1 + 32, Asl + 6144);
        load16(b0 + 32, Bsl + 4096); load16(b1 + 32, Bsl + 6144);
    }

    int sc = 0;   // consume slot (k%3)
    int sp = 2;   // prefetch slot ((k+2)%3)
    for (int k = 0; k < nIter; ++k) {
        if (k + 1 < nIter) {
            WAIT_VM(4);    // tile k landed; tile k+1 (4 loads) stays in flight
        } else {
            WAIT_VM(0);    // tail
        }
        BARRIER_RAW();     // all waves: tile-k landed, slot sp's old reads done
        if (k + 2 < nIter) {
            const int off = sp * 4096;
            const int k0 = (k + 2) << 5;
            load16(a0 + k0, Asl + off); load16(a1 + k0, Asl + off + 2048);
            load16(b0 + k0, Bsl + off); load16(b1 + k0, Bsl + off + 2048);
        }
        const _Float16* Ab = smem + sc * 4096;
        const _Float16* Bb = smem + 12288 + sc * 4096;
        half8 af[4], bf[4];
#pragma unroll
        for (int mt = 0; mt < 4; ++mt)
            af[mt] = *reinterpret_cast<const half8*>(Ab + (t.wm + mt * 16 + t.l16) * 32 + qsw);
#pragma unroll
        for (int nt = 0; nt < 4; ++nt)
            bf[nt] = *reinterpret_cast<const half8*>(Bb + (t.wn + nt * 16 + t.l16) * 32 + qsw);
#pragma unroll
        for (int mt = 0; mt < 4; ++mt)
#pragma unroll
            for (int nt = 0; nt < 4; ++nt)
                acc[mt][nt] = __builtin_amdgcn_mfma_f32_16x16x32_f16(af[mt], bf[nt], acc[mt][nt], 0, 0, 0);
        WAIT_LGKM0();      // pin my ds_reads before the next barrier (slot-overwrite guard)
        sc = (sc == 2) ? 0 : sc + 1;
        sp = (sp == 2) ? 0 : sp + 1;
    }
}

// ---------------------------------------------------------------- GEMM1: silu(H@Wi) -> u, vT, q, k
// 1D grid 1600, XCD-banded: xcd=f%8 owns m-band [8*xcd,8*xcd+8); n slow within band.
__global__ __launch_bounds__(256) void gemm1_kernel(
    const _Float16* __restrict__ Hb, const _Float16* __restrict__ WiT,
    const float* __restrict__ qg, const float* __restrict__ kg,
    _Float16* __restrict__ u, _Float16* __restrict__ vT,
    _Float16* __restrict__ q, _Float16* __restrict__ k)
{
    __shared__ _Float16 smem[24576];
    TileCtx t = make_ctx();
    const int f = blockIdx.x;
    const int xcd = f & 7, i = f >> 3;          // i: 0..199
    const int m0 = ((xcd << 3) | (i & 7)) * 128;
    const int n0 = (i >> 3) * 128;              // 0..24

    floatx4 acc[4][4] = {};
    gemm_mainloop_3s(t, Hb + (size_t)m0 * HID, HID, WiT + (size_t)n0 * HID, HID, HID, smem, acc);

    if (n0 >= INTER && n0 < 2 * INTER) {
        __syncthreads();   // mainloop has no trailing barrier; smem is reused below
        // vT path: transpose via LDS (XOR swizzle), then coalesced 16B stores.
        const int bb = m0 >> 11, sloc = m0 & (SEQ - 1), cI = n0 - INTER;
#pragma unroll
        for (int mt = 0; mt < 4; ++mt) {
#pragma unroll
            for (int nt = 0; nt < 4; ++nt) {
                int c = t.wn + nt * 16 + t.l16;
#pragma unroll
                for (int i2 = 0; i2 < 4; ++i2) {
                    int r = t.wm + mt * 16 + t.quad * 4 + i2;
                    float x = acc[mt][nt][i2];
                    float y = x / (1.0f + __expf(-x));   // silu
                    smem[c * 128 + (r ^ ((c & 15) << 3))] = (_Float16)y;
                }
            }
        }
        __syncthreads();
#pragma unroll
        for (int p = 0; p < 8; ++p) {
            int chunk = t.tid + p * 256;         // 2048 chunks of 8 halves
            int cl = chunk >> 4, sc = chunk & 15;
            int scs = sc ^ (cl & 15);
            half8 v = *reinterpret_cast<const half8*>(smem + cl * 128 + scs * 8);
            *reinterpret_cast<half8*>(vT + ((size_t)bb * INTER + cI + cl) * SEQ + sloc + sc * 8) = v;
        }
    } else {
#pragma unroll
        for (int mt = 0; mt < 4; ++mt) {
#pragma unroll
            for (int nt = 0; nt < 4; ++nt) {
                int col = n0 + t.wn + nt * 16 + t.l16;
#pragma unroll
                for (int i2 = 0; i2 < 4; ++i2) {
                    int row = m0 + t.wm + mt * 16 + t.quad * 4 + i2;
                    float x = acc[mt][nt][i2];
                    float y = x / (1.0f + __expf(-x));   // silu
                    if (n0 < INTER) {
                        u[(size_t)row * INTER + col] = (_Float16)y;
                    } else {
                        int c = col - 2 * INTER;
                        q[(size_t)row * DK + c] = (_Float16)(y * qg[c]);
                        k[(size_t)row * DK + c] = (_Float16)(y * kg[c]);
                    }
                }
            }
        }
    }
}

// ---------------------------------------------------------------- scores + softmax -> P (f16)
__global__ __launch_bounds__(256) void scores_kernel(
    const _Float16* __restrict__ q, const _Float16* __restrict__ k,
    const int* __restrict__ mask, const float* __restrict__ scales,
    _Float16* __restrict__ P)
{
    const int b = blockIdx.y;
    const int m0 = blockIdx.x * 16;
    const int tid = threadIdx.x;
    const int wave = tid >> 6, lane = tid & 63, quad = lane >> 4, l16 = lane & 15;
    const float scale = scales[b];

    half8 aq[4];
    const _Float16* qrow = q + (b * SEQ + m0 + l16) * DK + quad * 8;
#pragma unroll
    for (int kk = 0; kk < 4; ++kk) aq[kk] = *reinterpret_cast<const half8*>(qrow + kk * 32);

    floatx4 sc[32];
#pragma unroll
    for (int nt = 0; nt < 32; ++nt) {
        int n0 = nt * 64 + wave * 16;
        const _Float16* krow = k + (b * SEQ + n0 + l16) * DK + quad * 8;
        floatx4 acc = {};
#pragma unroll
        for (int kk = 0; kk < 4; ++kk) {
            half8 bq = *reinterpret_cast<const half8*>(krow + kk * 32);
            acc = __builtin_amdgcn_mfma_f32_16x16x32_f16(aq[kk], bq, acc, 0, 0, 0);
        }
        sc[nt] = acc;
    }

    const float rs = 0.08838834764831845f * scale;
    const float mval = -1e12f * scale;
    float rmax[4] = {-3.4e38f, -3.4e38f, -3.4e38f, -3.4e38f};
#pragma unroll
    for (int nt = 0; nt < 32; ++nt) {
        int ncol = nt * 64 + wave * 16 + l16;
        bool mok = mask[b * SEQ + ncol] != 0;
#pragma unroll
        for (int i = 0; i < 4; ++i) {
            float s = mok ? sc[nt][i] * rs : mval;
            sc[nt][i] = s;
            rmax[i] = fmaxf(rmax[i], s);
        }
    }
#pragma unroll
    for (int i = 0; i < 4; ++i) {
#pragma unroll
        for (int off = 1; off < 16; off <<= 1)
            rmax[i] = fmaxf(rmax[i], __shfl_xor(rmax[i], off, 64));
    }
    __shared__ float redmax[4][16];
    __shared__ float redsum[4][16];
    if (l16 == 0) {
#pragma unroll
        for (int i = 0; i < 4; ++i) redmax[wave][quad * 4 + i] = rmax[i];
    }
    __syncthreads();
#pragma unroll
    for (int i = 0; i < 4; ++i) {
        int r = quad * 4 + i;
        rmax[i] = fmaxf(fmaxf(redmax[0][r], redmax[1][r]), fmaxf(redmax[2][r], redmax[3][r]));
    }
    float rsum[4] = {0.f, 0.f, 0.f, 0.f};
#pragma unroll
    for (int nt = 0; nt < 32; ++nt) {
#pragma unroll
        for (int i = 0; i < 4; ++i) {
            float e = __expf(sc[nt][i] - rmax[i]);
            sc[nt][i] = e;
            rsum[i] += e;
        }
    }
#pragma unroll
    for (int i = 0; i < 4; ++i) {
#pragma unroll
        for (int off = 1; off < 16; off <<= 1) rsum[i] += __shfl_xor(rsum[i], off, 64);
    }
    if (l16 == 0) {
#pragma unroll
        for (int i = 0; i < 4; ++i) redsum[wave][quad * 4 + i] = rsum[i];
    }
    __syncthreads();
#pragma unroll
    for (int i = 0; i < 4; ++i) {
        int r = quad * 4 + i;
        float tot = redsum[0][r] + redsum[1][r] + redsum[2][r] + redsum[3][r];
        float inv = 1.0f / tot;
        int row = m0 + r;
        _Float16* Prow = P + ((size_t)b * SEQ + row) * SEQ;
#pragma unroll
        for (int nt = 0; nt < 32; ++nt) {
            int ncol = nt * 64 + wave * 16 + l16;
            Prow[ncol] = (_Float16)(sc[nt][i] * inv);
        }
    }
}

// ---------------------------------------------------------------- PV: u <- u .* (P @ v)   (in place)
// 1D grid 768: xcd=f%8, i=f/8 (0..95); batch=i/24; j=i%24; m=xcd*2+(j&1); n=j/2.
__global__ __launch_bounds__(256) void pv_kernel(
    const _Float16* __restrict__ P, const _Float16* __restrict__ vT,
    _Float16* __restrict__ u)
{
    __shared__ _Float16 smem[24576];
    TileCtx t = make_ctx();
    const int f = blockIdx.x;
    const int xcd = f & 7, i = f >> 3;          // i: 0..95
    const int b = i / 24, j = i % 24;
    const int m0 = (xcd * 2 + (j & 1)) * 128;
    const int n0 = (j >> 1) * 128;
    const _Float16* Pb  = P  + (size_t)b * SEQ * SEQ;
    const _Float16* vTb = vT + (size_t)b * INTER * SEQ;

    floatx4 acc[4][4] = {};
    gemm_mainloop_3s(t, Pb + (size_t)m0 * SEQ, SEQ, vTb + (size_t)n0 * SEQ, SEQ, SEQ, smem, acc);

#pragma unroll
    for (int mt = 0; mt < 4; ++mt) {
#pragma unroll
        for (int nt = 0; nt < 4; ++nt) {
            int col = n0 + t.wn + nt * 16 + t.l16;
#pragma unroll
            for (int i2 = 0; i2 < 4; ++i2) {
                int row = m0 + t.wm + mt * 16 + t.quad * 4 + i2;
                size_t gidx = ((size_t)(b * SEQ + row)) * INTER + col;
                float uv = (float)u[gidx];
                u[gidx] = (_Float16)(acc[mt][nt][i2] * uv);
            }
        }
    }
}

// ---------------------------------------------------------------- GEMM2: out = t @ Wo (fp32 out)
// 1D grid 384: xcd=f%8, i=f/8 (0..47); m=xcd*8+(i&7); n=i>>3 (0..5).
__global__ __launch_bounds__(256) void gemm2_kernel(
    const _Float16* __restrict__ tin, const _Float16* __restrict__ WoT,
    float* __restrict__ out)
{
    __shared__ _Float16 smem[24576];
    TileCtx t = make_ctx();
    const int f = blockIdx.x;
    const int xcd = f & 7, i = f >> 3;          // i: 0..47
    const int m0 = ((xcd << 3) | (i & 7)) * 128;
    const int n0 = (i >> 3) * 128;              // 0..5

    floatx4 acc[4][4] = {};
    gemm_mainloop_3s(t, tin + (size_t)m0 * INTER, INTER, WoT + (size_t)n0 * INTER, INTER, INTER, smem, acc);

#pragma unroll
    for (int mt = 0; mt < 4; ++mt) {
#pragma unroll
        for (int nt = 0; nt < 4; ++nt) {
            int col = n0 + t.wn + nt * 16 + t.l16;
#pragma unroll
            for (int i2 = 0; i2 < 4; ++i2) {
                int row = m0 + t.wm + mt * 16 + t.quad * 4 + i2;
                out[(size_t)row * HID + col] = acc[mt][nt][i2];
            }
        }
    }
}

// ---------------------------------------------------------------- launch
extern "C" void kernel_launch(void* const* d_in, const int* in_sizes, int n_in,
                              void* d_out, int out_size, void* d_ws, size_t ws_size,
                              hipStream_t stream) {
    const float* H    = (const float*)d_in[0];
    const float* Wi   = (const float*)d_in[1];
    const float* Wo   = (const float*)d_in[2];
    const float* qg   = (const float*)d_in[3];
    const float* kg   = (const float*)d_in[4];
    const int*   mask = (const int*)d_in[5];
    float* out = (float*)d_out;

    char* base = (char*)d_ws;
    size_t off = 0;
    auto alloc = [&](size_t bytes) { void* p = base + off; off = (off + bytes + 255) & ~(size_t)255; return p; };
    _Float16* Hb   = (_Float16*)alloc((size_t)MROWS * HID * 2);
    _Float16* WiT  = (_Float16*)alloc((size_t)NTOT * HID * 2);
    _Float16* WoT  = (_Float16*)alloc((size_t)HID * INTER * 2);
    _Float16* u    = (_Float16*)alloc((size_t)MROWS * INTER * 2);   // becomes t in-place after pv
    _Float16* vT   = (_Float16*)alloc((size_t)BATCH * INTER * SEQ * 2);
    _Float16* q    = (_Float16*)alloc((size_t)MROWS * DK * 2);
    _Float16* k    = (_Float16*)alloc((size_t)MROWS * DK * 2);
    _Float16* P    = (_Float16*)alloc((size_t)BATCH * SEQ * SEQ * 2);
    float*    scales = (float*)alloc(4 * sizeof(float));

    {
        int n = MROWS * HID;
        cast_h_kernel<<<n / 8 / 256, 256, 0, stream>>>(H, Hb, n);
        trans_wi_kernel<<<dim3(NTOT / 32, HID / 32), dim3(32, 8), 0, stream>>>(Wi, WiT);
        trans_wo_kernel<<<dim3(HID / 32, INTER / 32), dim3(32, 8), 0, stream>>>(Wo, WoT);
        mask_scales_kernel<<<BATCH, 256, 0, stream>>>(mask, scales);
    }
    // GEMM1: M=8192 N=3200 K=768
    gemm1_kernel<<<1600, 256, 0, stream>>>(Hb, WiT, qg, kg, u, vT, q, k);
    // scores + softmax -> P
    {
        dim3 grid(SEQ / 16, BATCH);
        scores_kernel<<<grid, 256, 0, stream>>>(q, k, mask, scales, P);
    }
    // PV: per batch M=2048 N=1536 K=2048
    pv_kernel<<<768, 256, 0, stream>>>(P, vT, u);
    // GEMM2: M=8192 N=768 K=1536
    gemm2_kernel<<<384, 256, 0, stream>>>(u, WoT, out);
}